// Round 6
// baseline (413.182 us; speedup 1.0000x reference)
//
#include <hip/hip_runtime.h>

typedef unsigned short ushort_t;
typedef unsigned int uint_t;

typedef float f32x4_t __attribute__((ext_vector_type(4)));
typedef short s16x8_t __attribute__((ext_vector_type(8)));

#define NB   256   // B
#define NG   512   // 2*B graphs
#define NPG  24    // nodes per graph
#define NMAXI 32   // N_MAX
#define EPG  200   // edges per graph
#define DD   256   // feature dim
// 1/TEMPERATURE * log2(e) = 10 * 1.4426950408889634
#define L2E_OVER_T 14.426950408889634f

__device__ __forceinline__ ushort_t f2bf(float f) {
    uint_t u = __float_as_uint(f);
    u += 0x7FFFu + ((u >> 16) & 1u);        // round-to-nearest-even
    return (ushort_t)(u >> 16);
}
__device__ __forceinline__ float bfhi(uint_t u) { return __uint_as_float(u & 0xFFFF0000u); }
__device__ __forceinline__ float bflo(uint_t u) { return __uint_as_float(u << 16); }

__device__ __forceinline__ float frcp(float x) {
#if __has_builtin(__builtin_amdgcn_rcpf)
    return __builtin_amdgcn_rcpf(x);
#else
    return 1.0f / x;
#endif
}

// Proven cross-lane butterflies (bit-exact match of the round-0 kernel).
__device__ __forceinline__ float red16(float s) {
    s += __shfl_xor(s, 1);
    s += __shfl_xor(s, 2);
    s += __shfl_xor(s, 4);
    s += __shfl_xor(s, 8);
    return s;   // all 16 lanes of the group hold the sum
}

// ---------------------------------------------------------------------------
// Kernel A: W1,W2 -> bf16 transposed ([n][k]), via LDS transpose.
// ---------------------------------------------------------------------------
__global__ __launch_bounds__(256) void prep_w(const float* __restrict__ W1,
                                              const float* __restrict__ W2,
                                              ushort_t* __restrict__ W1T,
                                              ushort_t* __restrict__ W2T)
{
    __shared__ float tile[2][4 * 256];
    const int t = threadIdx.x;
    const int k0 = blockIdx.x * 4;
    #pragma unroll
    for (int i = t; i < 4 * 256; i += 256) {
        tile[0][i] = W1[k0 * 256 + i];
        tile[1][i] = W2[k0 * 256 + i];
    }
    __syncthreads();
    const int n = t;
    #pragma unroll
    for (int m = 0; m < 2; ++m) {
        uint_t p0 = (uint_t)f2bf(tile[m][0 * 256 + n]) | ((uint_t)f2bf(tile[m][1 * 256 + n]) << 16);
        uint_t p1 = (uint_t)f2bf(tile[m][2 * 256 + n]) | ((uint_t)f2bf(tile[m][3 * 256 + n]) << 16);
        ushort_t* dst = (m ? W2T : W1T) + n * 256 + k0;
        uint2 pk; pk.x = p0; pk.y = p1;
        *(uint2*)dst = pk;
    }
}

// ---------------------------------------------------------------------------
// Kernel B: fused 2-layer MLP on the 12288 surviving edge rows (rank < 24).
// 768 blocks x 16 rows (verified correct in R4/R5).
// ---------------------------------------------------------------------------
__global__ __launch_bounds__(256) void mlp_kernel(
    const float* __restrict__ X, const ushort_t* __restrict__ W1T,
    const ushort_t* __restrict__ W2T, const float* __restrict__ b1,
    const float* __restrict__ b2, float* __restrict__ Y)
{
    __shared__ ushort_t sA[16 * 272];
    const int t = threadIdx.x;
    const int blk = blockIdx.x;           // 768 blocks x 16 rows
    const int lane = t & 63;
    const int w = t >> 6;                 // wave -> 64-col block
    const int quad = lane >> 4;
    const int mrow = lane & 15;

    {
        int r = t >> 4;                   // 16 rows, 16 threads/row
        int ch = (t & 15) * 16;           // 16 floats each
        int rho = blk * 16 + r;
        int g = rho / NPG;
        int e = rho - g * NPG;
        const float* src = X + ((size_t)(g * EPG + e)) * DD + ch;
        ushort_t* dst = &sA[r * 272 + ch];
        #pragma unroll
        for (int i = 0; i < 2; ++i) {
            float4 v0 = *(const float4*)(src + i * 8);
            float4 v1 = *(const float4*)(src + i * 8 + 4);
            uint4 pk;
            pk.x = (uint_t)f2bf(v0.x) | ((uint_t)f2bf(v0.y) << 16);
            pk.y = (uint_t)f2bf(v0.z) | ((uint_t)f2bf(v0.w) << 16);
            pk.z = (uint_t)f2bf(v1.x) | ((uint_t)f2bf(v1.y) << 16);
            pk.w = (uint_t)f2bf(v1.z) | ((uint_t)f2bf(v1.w) << 16);
            *(uint4*)(dst + i * 8) = pk;
        }
    }
    __syncthreads();

    f32x4_t acc[4];
    #pragma unroll
    for (int i = 0; i < 4; ++i) acc[i] = (f32x4_t){0.f, 0.f, 0.f, 0.f};

    #pragma unroll
    for (int k0 = 0; k0 < 256; k0 += 32) {
        s16x8_t a = *(const s16x8_t*)&sA[mrow * 272 + k0 + quad * 8];
        #pragma unroll
        for (int nt = 0; nt < 4; ++nt) {
            s16x8_t bb = *(const s16x8_t*)(W1T + (size_t)(64 * w + nt * 16 + mrow) * 256 + k0 + quad * 8);
            acc[nt] = __builtin_amdgcn_mfma_f32_16x16x32_bf16(a, bb, acc[nt], 0, 0, 0);
        }
    }
    __syncthreads();

    #pragma unroll
    for (int nt = 0; nt < 4; ++nt) {
        int col = 64 * w + nt * 16 + mrow;
        float bias = b1[col];
        f32x4_t v = acc[nt];
        #pragma unroll
        for (int reg = 0; reg < 4; ++reg) {
            int row = quad * 4 + reg;
            sA[row * 272 + col] = f2bf(fmaxf(v[reg] + bias, 0.f));
        }
    }
    __syncthreads();

    #pragma unroll
    for (int i = 0; i < 4; ++i) acc[i] = (f32x4_t){0.f, 0.f, 0.f, 0.f};

    #pragma unroll
    for (int k0 = 0; k0 < 256; k0 += 32) {
        s16x8_t a = *(const s16x8_t*)&sA[mrow * 272 + k0 + quad * 8];
        #pragma unroll
        for (int nt = 0; nt < 4; ++nt) {
            s16x8_t bb = *(const s16x8_t*)(W2T + (size_t)(64 * w + nt * 16 + mrow) * 256 + k0 + quad * 8);
            acc[nt] = __builtin_amdgcn_mfma_f32_16x16x32_bf16(a, bb, acc[nt], 0, 0, 0);
        }
    }

    #pragma unroll
    for (int nt = 0; nt < 4; ++nt) {
        int col = 64 * w + nt * 16 + mrow;
        float bias = b2[col];
        f32x4_t v = acc[nt];
        #pragma unroll
        for (int reg = 0; reg < 4; ++reg) {
            int row = blk * 16 + quad * 4 + reg;
            Y[(size_t)row * 256 + col] = v[reg] + bias;
        }
    }
}

// ---------------------------------------------------------------------------
// Kernel C: per-b fused K-build -> 20x linear-domain Sinkhorn -> score.
// v4:
//   - score phase split along d into 2 passes, ps[32] each: live set ~50 regs
//     fits the 64-VGPR budget -> no scratch spill regardless of allocator
//     behavior (R4/R5: 540-580 MB FETCH + 128 MB WRITE was ps[64] spill RMW
//     thrashing L2 -> HBM).
//   - __launch_bounds__(1024, 4): documented HIP route to cap at 4 waves/EU
//     (= the one 16-wave block the 256-block grid can resident anyway),
//     raising the VGPR budget to 128. Diagnostic: VGPR_Count > 64 => took.
//   - register-resident u_r, 2 barriers/iter, cf_s staging (all verified).
// ---------------------------------------------------------------------------
__global__ __launch_bounds__(1024, 4) void sink_kernel(
    const float* __restrict__ Tplan, const int* __restrict__ from_idx,
    const int* __restrict__ to_idx, const int* __restrict__ qsz,
    const int* __restrict__ csz, const float* __restrict__ qcf,
    float* __restrict__ out)
{
    const int b = blockIdx.x;
    const int t = threadIdx.x;
    const int R = t >> 4;      // row group: rows 4R..4R+3
    const int C = t & 15;      // col group: cols 16C..16C+15
    const int w = t >> 6;      // wave id (rows 16w..16w+15 live in wave w)

    // overlay region (phase-disjoint):
    //  build: Tl (33*33 f) @0, fq/tq/fc/tc @4368/5392/6416/7440
    //  iters: Vp [16][272] f @0 (17408 B)
    //  score: plan_s [256][25] f @0 (25600 B), cf_s @25600 ([24][320] swizzled)
    __shared__ __align__(16) char ovl[56320];
    __shared__ float rv_p[320];    // col chunk C at rv_p[20C..20C+15] (b128-aligned)
    __shared__ float wsum[16];

    float* Tl = (float*)ovl;
    int* fq = (int*)(ovl + 4368);
    int* tq = (int*)(ovl + 5392);
    int* fc = (int*)(ovl + 6416);
    int* tc = (int*)(ovl + 7440);
    float* Vp = (float*)ovl;               // [16][272]
    float* plan_s = (float*)ovl;           // [256][25]
    float* cf_s   = (float*)(ovl + 25600); // [24][320] swizzled chunks

    // --- phase 1: init ---
    for (int i = t; i < 33 * 33; i += 1024) Tl[i] = 0.f;
    if (t < 320) rv_p[t] = 1.0f;
    if (t < 256) {
        int gq = 2 * b, gc = 2 * b + 1;
        int a = NMAXI, bb = NMAXI, c = NMAXI, d = NMAXI;
        if (t < EPG) {
            a  = from_idx[gq * EPG + t] - gq * NPG;
            bb = to_idx  [gq * EPG + t] - gq * NPG;
            c  = from_idx[gc * EPG + t] - gc * NPG;
            d  = to_idx  [gc * EPG + t] - gc * NPG;
        }
        fq[t] = a; tq[t] = bb; fc[t] = c; tc[t] = d;
    }
    __syncthreads();
    {
        int i = t >> 5, j = t & 31;
        Tl[i * 33 + j] = Tplan[((size_t)b << 10) + t];
    }
    __syncthreads();

    // --- build K tile: Kp[i][u] packs cols (16C+2u, 16C+2u+1) of row 4R+i ---
    uint_t Kp[4][8];
    {
        int fcl[16], tcl[16];
        #pragma unroll
        for (int o = 0; o < 16; ++o) { fcl[o] = fc[16 * C + o]; tcl[o] = tc[16 * C + o]; }
        #pragma unroll
        for (int i = 0; i < 4; ++i) {
            const float* T1 = &Tl[fq[4 * R + i] * 33];
            const float* T2 = &Tl[tq[4 * R + i] * 33];
            #pragma unroll
            for (int u = 0; u < 8; ++u) {
                int f0 = fcl[2 * u], t0 = tcl[2 * u];
                int f1 = fcl[2 * u + 1], t1 = tcl[2 * u + 1];
                float la0 = T1[f0] * T2[t0] + T1[t0] * T2[f0];
                float la1 = T1[f1] * T2[t1] + T1[t1] * T2[f1];
                Kp[i][u] = (uint_t)f2bf(exp2f(la0 * L2E_OVER_T))
                         | ((uint_t)f2bf(exp2f(la1 * L2E_OVER_T)) << 16);
            }
        }
    }

    // --- 20 Sinkhorn iterations (2 barriers/iter) ---
    float u_r[4];
    for (int it = 0; it < 20; ++it) {
        // row step: U_r = 1 / sum_j K[r][j] * rv[j]  (register-resident)
        {
            float4 rv0 = *(const float4*)&rv_p[20 * C + 0];
            float4 rv1 = *(const float4*)&rv_p[20 * C + 4];
            float4 rv2 = *(const float4*)&rv_p[20 * C + 8];
            float4 rv3 = *(const float4*)&rv_p[20 * C + 12];
            #pragma unroll
            for (int i = 0; i < 4; ++i) {
                float a0 = bflo(Kp[i][0]) * rv0.x + bfhi(Kp[i][0]) * rv0.y;
                float a1 = bflo(Kp[i][1]) * rv0.z + bfhi(Kp[i][1]) * rv0.w;
                float a2 = bflo(Kp[i][2]) * rv1.x + bfhi(Kp[i][2]) * rv1.y;
                float a3 = bflo(Kp[i][3]) * rv1.z + bfhi(Kp[i][3]) * rv1.w;
                a0 += bflo(Kp[i][4]) * rv2.x + bfhi(Kp[i][4]) * rv2.y;
                a1 += bflo(Kp[i][5]) * rv2.z + bfhi(Kp[i][5]) * rv2.w;
                a2 += bflo(Kp[i][6]) * rv3.x + bfhi(Kp[i][6]) * rv3.y;
                a3 += bflo(Kp[i][7]) * rv3.z + bfhi(Kp[i][7]) * rv3.w;
                float s = (a0 + a1) + (a2 + a3);
                s = red16(s);             // all 16 C lanes hold the row sum
                u_r[i] = frcp(s);         // no LDS round-trip, no barrier
            }
        }
        // col step: V_j = sum_i K[i][j] * ru[i]
        {
            float u0 = u_r[0], u1 = u_r[1], u2 = u_r[2], u3 = u_r[3];
            float pc[16];
            #pragma unroll
            for (int u = 0; u < 8; ++u) {
                float e0 = bflo(Kp[0][u]) * u0 + bflo(Kp[1][u]) * u1
                         + bflo(Kp[2][u]) * u2 + bflo(Kp[3][u]) * u3;
                float e1 = bfhi(Kp[0][u]) * u0 + bfhi(Kp[1][u]) * u1
                         + bfhi(Kp[2][u]) * u2 + bfhi(Kp[3][u]) * u3;
                pc[2 * u] = e0; pc[2 * u + 1] = e1;
            }
            #pragma unroll
            for (int k = 0; k < 16; ++k) {
                float s = pc[k];
                s += __shfl_xor(s, 16);
                s += __shfl_xor(s, 32);
                pc[k] = s;
            }
            if ((t & 63) < 16) {   // one lane per C in this wave holds 16-row sums
                float* dst = &Vp[w * 272 + C * 16];
                *(float4*)(dst + 0)  = (float4){pc[0], pc[1], pc[2], pc[3]};
                *(float4*)(dst + 4)  = (float4){pc[4], pc[5], pc[6], pc[7]};
                *(float4*)(dst + 8)  = (float4){pc[8], pc[9], pc[10], pc[11]};
                *(float4*)(dst + 12) = (float4){pc[12], pc[13], pc[14], pc[15]};
            }
        }
        __syncthreads();
        if (t < 256) {   // second stage: sum the 16 wave partials
            float s = 0.f;
            #pragma unroll
            for (int ww = 0; ww < 16; ++ww) s += Vp[ww * 272 + t];
            rv_p[(t >> 4) * 20 + (t & 15)] = frcp(s);
        }
        __syncthreads();
    }

    // --- plan: plan_s[r][j] = K[r][j] * ru[r] * rv[j], j < 24 ---
    int nq = qsz[b]; if (nq > 24) nq = 24;
    int nc = csz[b]; if (nc > 24) nc = 24;

    if (C < 2) {
        int umax = (C == 0) ? 8 : 4;   // C=0: cols 0..15; C=1: cols 16..23
        #pragma unroll
        for (int i = 0; i < 4; ++i) {
            float rr = u_r[i];
            for (int u = 0; u < umax; ++u) {
                int j = 16 * C + 2 * u;
                plan_s[(4 * R + i) * 25 + j]     = bflo(Kp[i][u]) * rr * rv_p[20 * C + 2 * u];
                plan_s[(4 * R + i) * 25 + j + 1] = bfhi(Kp[i][u]) * rr * rv_p[20 * C + 2 * u + 1];
            }
        }
    }
    if (t < 768) {  // cf rows -> swizzled LDS chunks of 16 floats @ stride 20
        int j = t >> 5, inner = t & 31;
        int c = inner * 8;
        const float* src = qcf + ((size_t)(2 * b + 1) * 24 + j) * 256 + c;
        float4 v0 = *(const float4*)(src);
        float4 v1 = *(const float4*)(src + 4);
        float* dst = cf_s + j * 320 + (c >> 4) * 20 + (c & 15);
        *(float4*)dst = v0;
        *(float4*)(dst + 4) = v1;
    }
    __syncthreads();

    // --- score: thread = rows 4R..4R+3 x cols 16C..16C+15, 2 d-passes ---
    // pass p covers float4 slots k = 2p, 2p+1 (8 d-values); ps[32] per pass
    // keeps the live set ~50 VGPRs -> guaranteed no scratch spill.
    const int r0 = R * 4;
    const int m  = C;
    const float* qbase = qcf + (size_t)(2 * b) * 24 * 256;

    float ssum = 0.f;
    #pragma unroll
    for (int p = 0; p < 2; ++p) {
        float ps[32];
        #pragma unroll
        for (int i = 0; i < 32; ++i) ps[i] = 0.f;

        for (int j = 0; j < nc; ++j) {
            float p0 = plan_s[(r0 + 0) * 25 + j];
            float p1 = plan_s[(r0 + 1) * 25 + j];
            float p2 = plan_s[(r0 + 2) * 25 + j];
            float p3 = plan_s[(r0 + 3) * 25 + j];
            const float4* cfp = (const float4*)(cf_s + j * 320 + m * 20) + 2 * p;
            #pragma unroll
            for (int k = 0; k < 2; ++k) {
                float4 cv = cfp[k];
                ps[ 0 + k * 4 + 0] += p0 * cv.x; ps[ 0 + k * 4 + 1] += p0 * cv.y;
                ps[ 0 + k * 4 + 2] += p0 * cv.z; ps[ 0 + k * 4 + 3] += p0 * cv.w;
                ps[ 8 + k * 4 + 0] += p1 * cv.x; ps[ 8 + k * 4 + 1] += p1 * cv.y;
                ps[ 8 + k * 4 + 2] += p1 * cv.z; ps[ 8 + k * 4 + 3] += p1 * cv.w;
                ps[16 + k * 4 + 0] += p2 * cv.x; ps[16 + k * 4 + 1] += p2 * cv.y;
                ps[16 + k * 4 + 2] += p2 * cv.z; ps[16 + k * 4 + 3] += p2 * cv.w;
                ps[24 + k * 4 + 0] += p3 * cv.x; ps[24 + k * 4 + 1] += p3 * cv.y;
                ps[24 + k * 4 + 2] += p3 * cv.z; ps[24 + k * 4 + 3] += p3 * cv.w;
            }
        }

        #pragma unroll
        for (int i = 0; i < 4; ++i) {
            int row = r0 + i;
            if (row < nq) {
                const float4* qp = (const float4*)(qbase + (size_t)row * 256 + m * 16) + 2 * p;
                #pragma unroll
                for (int k = 0; k < 2; ++k) {
                    float4 qv = qp[k];
                    ssum += fmaxf(qv.x - ps[i * 8 + k * 4 + 0], 0.f);
                    ssum += fmaxf(qv.y - ps[i * 8 + k * 4 + 1], 0.f);
                    ssum += fmaxf(qv.z - ps[i * 8 + k * 4 + 2], 0.f);
                    ssum += fmaxf(qv.w - ps[i * 8 + k * 4 + 3], 0.f);
                }
            } else {
                #pragma unroll
                for (int k = 0; k < 8; ++k) ssum += fmaxf(-ps[i * 8 + k], 0.f);
            }
        }
    }

    ssum += __shfl_xor(ssum, 1);
    ssum += __shfl_xor(ssum, 2);
    ssum += __shfl_xor(ssum, 4);
    ssum += __shfl_xor(ssum, 8);
    ssum += __shfl_xor(ssum, 16);
    ssum += __shfl_xor(ssum, 32);
    if ((t & 63) == 0) wsum[t >> 6] = ssum;
    __syncthreads();
    if (t == 0) {
        float s = 0.f;
        #pragma unroll
        for (int i = 0; i < 16; ++i) s += wsum[i];
        out[b] = -s;
    }
}

// ---------------------------------------------------------------------------
extern "C" void kernel_launch(void* const* d_in, const int* in_sizes, int n_in,
                              void* d_out, int out_size, void* d_ws, size_t ws_size,
                              hipStream_t stream)
{
    const float* edge_feat = (const float*)d_in[0];
    const float* tplan     = (const float*)d_in[1];
    const float* W1        = (const float*)d_in[2];
    const float* b1        = (const float*)d_in[3];
    const float* W2        = (const float*)d_in[4];
    const float* b2        = (const float*)d_in[5];
    const int*   from_idx  = (const int*)d_in[6];
    const int*   to_idx    = (const int*)d_in[7];
    const int*   qsz       = (const int*)d_in[9];
    const int*   csz       = (const int*)d_in[10];
    float* out = (float*)d_out;

    // workspace: [0,128K) W1T bf16 | [128K,256K) W2T bf16 | [256K,+12.6MB) qcf f32
    char* ws = (char*)d_ws;
    ushort_t* W1T = (ushort_t*)ws;
    ushort_t* W2T = W1T + 65536;
    float* qcf = (float*)(ws + 262144);

    prep_w<<<64, 256, 0, stream>>>(W1, W2, W1T, W2T);
    mlp_kernel<<<768, 256, 0, stream>>>(edge_feat, W1T, W2T, b1, b2, qcf);
    sink_kernel<<<256, 1024, 0, stream>>>(tplan, from_idx, to_idx, qsz, csz, qcf, out);
}

// Round 7
// 273.929 us; speedup vs baseline: 1.5084x; 1.5084x over previous
//
#include <hip/hip_runtime.h>

typedef unsigned short ushort_t;
typedef unsigned int uint_t;

typedef float f32x4_t __attribute__((ext_vector_type(4)));
typedef short s16x8_t __attribute__((ext_vector_type(8)));

#define NB   256   // B
#define NG   512   // 2*B graphs
#define NPG  24    // nodes per graph
#define NMAXI 32   // N_MAX
#define EPG  200   // edges per graph
#define DD   256   // feature dim
// 1/TEMPERATURE * log2(e) = 10 * 1.4426950408889634
#define L2E_OVER_T 14.426950408889634f

__device__ __forceinline__ ushort_t f2bf(float f) {
    uint_t u = __float_as_uint(f);
    u += 0x7FFFu + ((u >> 16) & 1u);        // round-to-nearest-even
    return (ushort_t)(u >> 16);
}
__device__ __forceinline__ float bfhi(uint_t u) { return __uint_as_float(u & 0xFFFF0000u); }
__device__ __forceinline__ float bflo(uint_t u) { return __uint_as_float(u << 16); }

__device__ __forceinline__ float frcp(float x) {
#if __has_builtin(__builtin_amdgcn_rcpf)
    return __builtin_amdgcn_rcpf(x);
#else
    return 1.0f / x;
#endif
}

// ---------------------------------------------------------------------------
// Kernel A: W1,W2 -> bf16 transposed ([n][k]), via LDS transpose.
// ---------------------------------------------------------------------------
__global__ __launch_bounds__(256) void prep_w(const float* __restrict__ W1,
                                              const float* __restrict__ W2,
                                              ushort_t* __restrict__ W1T,
                                              ushort_t* __restrict__ W2T)
{
    __shared__ float tile[2][4 * 256];
    const int t = threadIdx.x;
    const int k0 = blockIdx.x * 4;
    #pragma unroll
    for (int i = t; i < 4 * 256; i += 256) {
        tile[0][i] = W1[k0 * 256 + i];
        tile[1][i] = W2[k0 * 256 + i];
    }
    __syncthreads();
    const int n = t;
    #pragma unroll
    for (int m = 0; m < 2; ++m) {
        uint_t p0 = (uint_t)f2bf(tile[m][0 * 256 + n]) | ((uint_t)f2bf(tile[m][1 * 256 + n]) << 16);
        uint_t p1 = (uint_t)f2bf(tile[m][2 * 256 + n]) | ((uint_t)f2bf(tile[m][3 * 256 + n]) << 16);
        ushort_t* dst = (m ? W2T : W1T) + n * 256 + k0;
        uint2 pk; pk.x = p0; pk.y = p1;
        *(uint2*)dst = pk;
    }
}

// ---------------------------------------------------------------------------
// Kernel B: fused 2-layer MLP on the 12288 surviving edge rows (rank < 24).
// 768 blocks x 16 rows (verified correct R4/R5/R6).
// ---------------------------------------------------------------------------
__global__ __launch_bounds__(256) void mlp_kernel(
    const float* __restrict__ X, const ushort_t* __restrict__ W1T,
    const ushort_t* __restrict__ W2T, const float* __restrict__ b1,
    const float* __restrict__ b2, float* __restrict__ Y)
{
    __shared__ ushort_t sA[16 * 272];
    const int t = threadIdx.x;
    const int blk = blockIdx.x;           // 768 blocks x 16 rows
    const int lane = t & 63;
    const int w = t >> 6;                 // wave -> 64-col block
    const int quad = lane >> 4;
    const int mrow = lane & 15;

    {
        int r = t >> 4;                   // 16 rows, 16 threads/row
        int ch = (t & 15) * 16;           // 16 floats each
        int rho = blk * 16 + r;
        int g = rho / NPG;
        int e = rho - g * NPG;
        const float* src = X + ((size_t)(g * EPG + e)) * DD + ch;
        ushort_t* dst = &sA[r * 272 + ch];
        #pragma unroll
        for (int i = 0; i < 2; ++i) {
            float4 v0 = *(const float4*)(src + i * 8);
            float4 v1 = *(const float4*)(src + i * 8 + 4);
            uint4 pk;
            pk.x = (uint_t)f2bf(v0.x) | ((uint_t)f2bf(v0.y) << 16);
            pk.y = (uint_t)f2bf(v0.z) | ((uint_t)f2bf(v0.w) << 16);
            pk.z = (uint_t)f2bf(v1.x) | ((uint_t)f2bf(v1.y) << 16);
            pk.w = (uint_t)f2bf(v1.z) | ((uint_t)f2bf(v1.w) << 16);
            *(uint4*)(dst + i * 8) = pk;
        }
    }
    __syncthreads();

    f32x4_t acc[4];
    #pragma unroll
    for (int i = 0; i < 4; ++i) acc[i] = (f32x4_t){0.f, 0.f, 0.f, 0.f};

    #pragma unroll
    for (int k0 = 0; k0 < 256; k0 += 32) {
        s16x8_t a = *(const s16x8_t*)&sA[mrow * 272 + k0 + quad * 8];
        #pragma unroll
        for (int nt = 0; nt < 4; ++nt) {
            s16x8_t bb = *(const s16x8_t*)(W1T + (size_t)(64 * w + nt * 16 + mrow) * 256 + k0 + quad * 8);
            acc[nt] = __builtin_amdgcn_mfma_f32_16x16x32_bf16(a, bb, acc[nt], 0, 0, 0);
        }
    }
    __syncthreads();

    #pragma unroll
    for (int nt = 0; nt < 4; ++nt) {
        int col = 64 * w + nt * 16 + mrow;
        float bias = b1[col];
        f32x4_t v = acc[nt];
        #pragma unroll
        for (int reg = 0; reg < 4; ++reg) {
            int row = quad * 4 + reg;
            sA[row * 272 + col] = f2bf(fmaxf(v[reg] + bias, 0.f));
        }
    }
    __syncthreads();

    #pragma unroll
    for (int i = 0; i < 4; ++i) acc[i] = (f32x4_t){0.f, 0.f, 0.f, 0.f};

    #pragma unroll
    for (int k0 = 0; k0 < 256; k0 += 32) {
        s16x8_t a = *(const s16x8_t*)&sA[mrow * 272 + k0 + quad * 8];
        #pragma unroll
        for (int nt = 0; nt < 4; ++nt) {
            s16x8_t bb = *(const s16x8_t*)(W2T + (size_t)(64 * w + nt * 16 + mrow) * 256 + k0 + quad * 8);
            acc[nt] = __builtin_amdgcn_mfma_f32_16x16x32_bf16(a, bb, acc[nt], 0, 0, 0);
        }
    }

    #pragma unroll
    for (int nt = 0; nt < 4; ++nt) {
        int col = 64 * w + nt * 16 + mrow;
        float bias = b2[col];
        f32x4_t v = acc[nt];
        #pragma unroll
        for (int reg = 0; reg < 4; ++reg) {
            int row = blk * 16 + quad * 4 + reg;
            Y[(size_t)row * 256 + col] = v[reg] + bias;
        }
    }
}

// ---------------------------------------------------------------------------
// Kernel C: per-b fused K-build -> 20x linear-domain Sinkhorn -> score.
// v5 = exact R0 Sinkhorn structure (LDS ru_s row step, 3 barriers/iter —
// the only config with a verified-good memory profile: 112 us, 28/46 MB),
// plus two strictly pressure-REDUCING local tweaks:
//   - col step computed in two pc[8] halves (same math/shfl count)
//   - score phase in two ps[32] d-passes (R6-verified)
// Register-resident u_r is REVERTED: its loop-crossing liveness caused the
// Kp/pc spill storm (R4-R6: 580 MB fetch / 140 MB write, 250 us).
// ---------------------------------------------------------------------------
__global__ __launch_bounds__(1024) void sink_kernel(
    const float* __restrict__ Tplan, const int* __restrict__ from_idx,
    const int* __restrict__ to_idx, const int* __restrict__ qsz,
    const int* __restrict__ csz, const float* __restrict__ qcf,
    float* __restrict__ out)
{
    const int b = blockIdx.x;
    const int t = threadIdx.x;
    const int R = t >> 4;      // row group: rows 4R..4R+3
    const int C = t & 15;      // col group: cols 16C..16C+15
    const int w = t >> 6;      // wave id (rows 16w..16w+15 live in wave w)

    // overlay region (phase-disjoint):
    //  build: Tl (33*33 f) @0, fq/tq/fc/tc @4368/5392/6416/7440
    //  iters: Vp [16][272] f @0 (17408 B)
    //  score: plan_s [256][25] f @0, cf_s @25600 ([24][16*20] swizzled)
    __shared__ __align__(16) char ovl[56320];
    __shared__ float ru_s[260];
    __shared__ float rv_p[320];    // col chunk C at rv_p[20C..20C+15] (b128-aligned)
    __shared__ float wsum[16];

    float* Tl = (float*)ovl;
    int* fq = (int*)(ovl + 4368);
    int* tq = (int*)(ovl + 5392);
    int* fc = (int*)(ovl + 6416);
    int* tc = (int*)(ovl + 7440);
    float* Vp = (float*)ovl;               // [16][272]
    float* plan_s = (float*)ovl;           // [256][25]
    float* cf_s   = (float*)(ovl + 25600);

    // --- phase 1: init ---
    for (int i = t; i < 33 * 33; i += 1024) Tl[i] = 0.f;
    if (t < 320) rv_p[t] = 1.0f;
    if (t < 256) {
        int gq = 2 * b, gc = 2 * b + 1;
        int a = NMAXI, bb = NMAXI, c = NMAXI, d = NMAXI;
        if (t < EPG) {
            a  = from_idx[gq * EPG + t] - gq * NPG;
            bb = to_idx  [gq * EPG + t] - gq * NPG;
            c  = from_idx[gc * EPG + t] - gc * NPG;
            d  = to_idx  [gc * EPG + t] - gc * NPG;
        }
        fq[t] = a; tq[t] = bb; fc[t] = c; tc[t] = d;
    }
    __syncthreads();
    {
        int i = t >> 5, j = t & 31;
        Tl[i * 33 + j] = Tplan[((size_t)b << 10) + t];
    }
    __syncthreads();

    // --- build K tile: Kp[i][u] packs cols (16C+2u, 16C+2u+1) of row 4R+i ---
    uint_t Kp[4][8];
    {
        int fcl[16], tcl[16];
        #pragma unroll
        for (int o = 0; o < 16; ++o) { fcl[o] = fc[16 * C + o]; tcl[o] = tc[16 * C + o]; }
        #pragma unroll
        for (int i = 0; i < 4; ++i) {
            const float* T1 = &Tl[fq[4 * R + i] * 33];
            const float* T2 = &Tl[tq[4 * R + i] * 33];
            #pragma unroll
            for (int u = 0; u < 8; ++u) {
                int f0 = fcl[2 * u], t0 = tcl[2 * u];
                int f1 = fcl[2 * u + 1], t1 = tcl[2 * u + 1];
                float la0 = T1[f0] * T2[t0] + T1[t0] * T2[f0];
                float la1 = T1[f1] * T2[t1] + T1[t1] * T2[f1];
                Kp[i][u] = (uint_t)f2bf(exp2f(la0 * L2E_OVER_T))
                         | ((uint_t)f2bf(exp2f(la1 * L2E_OVER_T)) << 16);
            }
        }
    }

    // --- 20 Sinkhorn iterations (R0 structure: 3 barriers/iter) ---
    for (int it = 0; it < 20; ++it) {
        // row step: U_r = sum_j K[r][j] * rv[j]
        {
            float4 rv0 = *(const float4*)&rv_p[20 * C + 0];
            float4 rv1 = *(const float4*)&rv_p[20 * C + 4];
            float4 rv2 = *(const float4*)&rv_p[20 * C + 8];
            float4 rv3 = *(const float4*)&rv_p[20 * C + 12];
            float pr[4];
            #pragma unroll
            for (int i = 0; i < 4; ++i) {
                float a0 = bflo(Kp[i][0]) * rv0.x + bfhi(Kp[i][0]) * rv0.y;
                float a1 = bflo(Kp[i][1]) * rv0.z + bfhi(Kp[i][1]) * rv0.w;
                float a2 = bflo(Kp[i][2]) * rv1.x + bfhi(Kp[i][2]) * rv1.y;
                float a3 = bflo(Kp[i][3]) * rv1.z + bfhi(Kp[i][3]) * rv1.w;
                a0 += bflo(Kp[i][4]) * rv2.x + bfhi(Kp[i][4]) * rv2.y;
                a1 += bflo(Kp[i][5]) * rv2.z + bfhi(Kp[i][5]) * rv2.w;
                a2 += bflo(Kp[i][6]) * rv3.x + bfhi(Kp[i][6]) * rv3.y;
                a3 += bflo(Kp[i][7]) * rv3.z + bfhi(Kp[i][7]) * rv3.w;
                pr[i] = (a0 + a1) + (a2 + a3);
            }
            #pragma unroll
            for (int i = 0; i < 4; ++i) {
                float s = pr[i];
                s += __shfl_xor(s, 1);
                s += __shfl_xor(s, 2);
                s += __shfl_xor(s, 4);
                s += __shfl_xor(s, 8);
                pr[i] = s;
            }
            if (C == 0) {
                #pragma unroll
                for (int i = 0; i < 4; ++i) ru_s[4 * R + i] = frcp(pr[i]);
            }
        }
        __syncthreads();
        // col step: V_j = sum_i K[i][j] * ru[i]  (two pc[8] halves)
        {
            float u0 = ru_s[4 * R + 0], u1 = ru_s[4 * R + 1];
            float u2 = ru_s[4 * R + 2], u3 = ru_s[4 * R + 3];
            #pragma unroll
            for (int h = 0; h < 2; ++h) {
                float pc[8];
                #pragma unroll
                for (int u = 0; u < 4; ++u) {
                    int uu = 4 * h + u;
                    float e0 = bflo(Kp[0][uu]) * u0 + bflo(Kp[1][uu]) * u1
                             + bflo(Kp[2][uu]) * u2 + bflo(Kp[3][uu]) * u3;
                    float e1 = bfhi(Kp[0][uu]) * u0 + bfhi(Kp[1][uu]) * u1
                             + bfhi(Kp[2][uu]) * u2 + bfhi(Kp[3][uu]) * u3;
                    pc[2 * u] = e0; pc[2 * u + 1] = e1;
                }
                #pragma unroll
                for (int k = 0; k < 8; ++k) {
                    float s = pc[k];
                    s += __shfl_xor(s, 16);
                    s += __shfl_xor(s, 32);
                    pc[k] = s;
                }
                if ((t & 63) < 16) {   // one lane per C holds 16-row sums
                    float* dst = &Vp[w * 272 + C * 16 + 8 * h];
                    *(float4*)(dst + 0) = (float4){pc[0], pc[1], pc[2], pc[3]};
                    *(float4*)(dst + 4) = (float4){pc[4], pc[5], pc[6], pc[7]};
                }
            }
        }
        __syncthreads();
        if (t < 256) {   // second stage: sum the 16 wave partials
            float s = 0.f;
            #pragma unroll
            for (int ww = 0; ww < 16; ++ww) s += Vp[ww * 272 + t];
            rv_p[(t >> 4) * 20 + (t & 15)] = frcp(s);
        }
        __syncthreads();
    }

    // --- plan: plan_s[r][j] = K[r][j] * ru[r] * rv[j], j < 24 ---
    int nq = qsz[b]; if (nq > 24) nq = 24;
    int nc = csz[b]; if (nc > 24) nc = 24;

    if (C < 2) {
        int umax = (C == 0) ? 8 : 4;   // C=0: cols 0..15; C=1: cols 16..23
        #pragma unroll
        for (int i = 0; i < 4; ++i) {
            float rr = ru_s[4 * R + i];
            for (int u = 0; u < umax; ++u) {
                int j = 16 * C + 2 * u;
                plan_s[(4 * R + i) * 25 + j]     = bflo(Kp[i][u]) * rr * rv_p[20 * C + 2 * u];
                plan_s[(4 * R + i) * 25 + j + 1] = bfhi(Kp[i][u]) * rr * rv_p[20 * C + 2 * u + 1];
            }
        }
    }
    if (t < 768) {  // cf rows -> swizzled LDS chunks of 16 floats @ stride 20
        int j = t >> 5, inner = t & 31;
        int c = inner * 8;
        const float* src = qcf + ((size_t)(2 * b + 1) * 24 + j) * 256 + c;
        float4 v0 = *(const float4*)(src);
        float4 v1 = *(const float4*)(src + 4);
        float* dst = cf_s + j * 320 + (c >> 4) * 20 + (c & 15);
        *(float4*)dst = v0;
        *(float4*)(dst + 4) = v1;
    }
    __syncthreads();

    // --- score: thread = rows 4R..4R+3 x cols 16C..16C+15, 2 d-passes ---
    const int r0 = R * 4;
    const int m  = C;
    const float* qbase = qcf + (size_t)(2 * b) * 24 * 256;

    float ssum = 0.f;
    #pragma unroll
    for (int p = 0; p < 2; ++p) {
        float ps[32];
        #pragma unroll
        for (int i = 0; i < 32; ++i) ps[i] = 0.f;

        for (int j = 0; j < nc; ++j) {
            float p0 = plan_s[(r0 + 0) * 25 + j];
            float p1 = plan_s[(r0 + 1) * 25 + j];
            float p2 = plan_s[(r0 + 2) * 25 + j];
            float p3 = plan_s[(r0 + 3) * 25 + j];
            const float4* cfp = (const float4*)(cf_s + j * 320 + m * 20) + 2 * p;
            #pragma unroll
            for (int k = 0; k < 2; ++k) {
                float4 cv = cfp[k];
                ps[ 0 + k * 4 + 0] += p0 * cv.x; ps[ 0 + k * 4 + 1] += p0 * cv.y;
                ps[ 0 + k * 4 + 2] += p0 * cv.z; ps[ 0 + k * 4 + 3] += p0 * cv.w;
                ps[ 8 + k * 4 + 0] += p1 * cv.x; ps[ 8 + k * 4 + 1] += p1 * cv.y;
                ps[ 8 + k * 4 + 2] += p1 * cv.z; ps[ 8 + k * 4 + 3] += p1 * cv.w;
                ps[16 + k * 4 + 0] += p2 * cv.x; ps[16 + k * 4 + 1] += p2 * cv.y;
                ps[16 + k * 4 + 2] += p2 * cv.z; ps[16 + k * 4 + 3] += p2 * cv.w;
                ps[24 + k * 4 + 0] += p3 * cv.x; ps[24 + k * 4 + 1] += p3 * cv.y;
                ps[24 + k * 4 + 2] += p3 * cv.z; ps[24 + k * 4 + 3] += p3 * cv.w;
            }
        }

        #pragma unroll
        for (int i = 0; i < 4; ++i) {
            int row = r0 + i;
            if (row < nq) {
                const float4* qp = (const float4*)(qbase + (size_t)row * 256 + m * 16) + 2 * p;
                #pragma unroll
                for (int k = 0; k < 2; ++k) {
                    float4 qv = qp[k];
                    ssum += fmaxf(qv.x - ps[i * 8 + k * 4 + 0], 0.f);
                    ssum += fmaxf(qv.y - ps[i * 8 + k * 4 + 1], 0.f);
                    ssum += fmaxf(qv.z - ps[i * 8 + k * 4 + 2], 0.f);
                    ssum += fmaxf(qv.w - ps[i * 8 + k * 4 + 3], 0.f);
                }
            } else {
                #pragma unroll
                for (int k = 0; k < 8; ++k) ssum += fmaxf(-ps[i * 8 + k], 0.f);
            }
        }
    }

    ssum += __shfl_xor(ssum, 1);
    ssum += __shfl_xor(ssum, 2);
    ssum += __shfl_xor(ssum, 4);
    ssum += __shfl_xor(ssum, 8);
    ssum += __shfl_xor(ssum, 16);
    ssum += __shfl_xor(ssum, 32);
    if ((t & 63) == 0) wsum[t >> 6] = ssum;
    __syncthreads();
    if (t == 0) {
        float s = 0.f;
        #pragma unroll
        for (int i = 0; i < 16; ++i) s += wsum[i];
        out[b] = -s;
    }
}

// ---------------------------------------------------------------------------
extern "C" void kernel_launch(void* const* d_in, const int* in_sizes, int n_in,
                              void* d_out, int out_size, void* d_ws, size_t ws_size,
                              hipStream_t stream)
{
    const float* edge_feat = (const float*)d_in[0];
    const float* tplan     = (const float*)d_in[1];
    const float* W1        = (const float*)d_in[2];
    const float* b1        = (const float*)d_in[3];
    const float* W2        = (const float*)d_in[4];
    const float* b2        = (const float*)d_in[5];
    const int*   from_idx  = (const int*)d_in[6];
    const int*   to_idx    = (const int*)d_in[7];
    const int*   qsz       = (const int*)d_in[9];
    const int*   csz       = (const int*)d_in[10];
    float* out = (float*)d_out;

    // workspace: [0,128K) W1T bf16 | [128K,256K) W2T bf16 | [256K,+12.6MB) qcf f32
    char* ws = (char*)d_ws;
    ushort_t* W1T = (ushort_t*)ws;
    ushort_t* W2T = W1T + 65536;
    float* qcf = (float*)(ws + 262144);

    prep_w<<<64, 256, 0, stream>>>(W1, W2, W1T, W2T);
    mlp_kernel<<<768, 256, 0, stream>>>(edge_feat, W1T, W2T, b1, b2, qcf);
    sink_kernel<<<256, 1024, 0, stream>>>(tplan, from_idx, to_idx, qsz, csz, qcf, out);
}

// Round 8
// 265.471 us; speedup vs baseline: 1.5564x; 1.0319x over previous
//
#include <hip/hip_runtime.h>

typedef unsigned short ushort_t;
typedef unsigned int uint_t;

typedef float f32x4_t __attribute__((ext_vector_type(4)));
typedef short s16x8_t __attribute__((ext_vector_type(8)));

#define NB   256   // B
#define NG   512   // 2*B graphs
#define NPG  24    // nodes per graph
#define NMAXI 32   // N_MAX
#define EPG  200   // edges per graph
#define DD   256   // feature dim
// 1/TEMPERATURE * log2(e) = 10 * 1.4426950408889634
#define L2E_OVER_T 14.426950408889634f

__device__ __forceinline__ ushort_t f2bf(float f) {
    uint_t u = __float_as_uint(f);
    u += 0x7FFFu + ((u >> 16) & 1u);        // round-to-nearest-even
    return (ushort_t)(u >> 16);
}
__device__ __forceinline__ float bfhi(uint_t u) { return __uint_as_float(u & 0xFFFF0000u); }
__device__ __forceinline__ float bflo(uint_t u) { return __uint_as_float(u << 16); }

__device__ __forceinline__ float frcp(float x) {
#if __has_builtin(__builtin_amdgcn_rcpf)
    return __builtin_amdgcn_rcpf(x);
#else
    return 1.0f / x;
#endif
}

// ---- DPP 16-lane reduction on the VALU pipe (canonical rocPRIM pattern) ---
// Each level's partner group holds a group-uniform partial, so mirror levels
// are exact butterfly substitutes:
//   0xB1 quad_perm[1,0,3,2] = xor1; 0x4E quad_perm[2,3,0,1] = xor2;
//   0x141 row_half_mirror (xor4-equiv after L1,L2); 0x140 row_mirror (xor8).
template <int CTRL>
__device__ __forceinline__ float dpp_radd(float s) {
    int d = __builtin_amdgcn_update_dpp(0, __float_as_int(s), CTRL, 0xF, 0xF, true);
    return s + __int_as_float(d);
}
__device__ __forceinline__ float row16_reduce_dpp(float s) {
    s = dpp_radd<0xB1>(s);
    s = dpp_radd<0x4E>(s);
    s = dpp_radd<0x141>(s);
    s = dpp_radd<0x140>(s);
    return s;   // all 16 lanes of the group hold the sum
}

// ---------------------------------------------------------------------------
// Kernel A: W1,W2 -> bf16 transposed ([n][k]), via LDS transpose.
// ---------------------------------------------------------------------------
__global__ __launch_bounds__(256) void prep_w(const float* __restrict__ W1,
                                              const float* __restrict__ W2,
                                              ushort_t* __restrict__ W1T,
                                              ushort_t* __restrict__ W2T)
{
    __shared__ float tile[2][4 * 256];
    const int t = threadIdx.x;
    const int k0 = blockIdx.x * 4;
    #pragma unroll
    for (int i = t; i < 4 * 256; i += 256) {
        tile[0][i] = W1[k0 * 256 + i];
        tile[1][i] = W2[k0 * 256 + i];
    }
    __syncthreads();
    const int n = t;
    #pragma unroll
    for (int m = 0; m < 2; ++m) {
        uint_t p0 = (uint_t)f2bf(tile[m][0 * 256 + n]) | ((uint_t)f2bf(tile[m][1 * 256 + n]) << 16);
        uint_t p1 = (uint_t)f2bf(tile[m][2 * 256 + n]) | ((uint_t)f2bf(tile[m][3 * 256 + n]) << 16);
        ushort_t* dst = (m ? W2T : W1T) + n * 256 + k0;
        uint2 pk; pk.x = p0; pk.y = p1;
        *(uint2*)dst = pk;
    }
}

// ---------------------------------------------------------------------------
// Kernel B: fused 2-layer MLP on the 12288 surviving edge rows (rank < 24).
// 768 blocks x 16 rows (verified correct R4-R7).
// ---------------------------------------------------------------------------
__global__ __launch_bounds__(256) void mlp_kernel(
    const float* __restrict__ X, const ushort_t* __restrict__ W1T,
    const ushort_t* __restrict__ W2T, const float* __restrict__ b1,
    const float* __restrict__ b2, float* __restrict__ Y)
{
    __shared__ ushort_t sA[16 * 272];
    const int t = threadIdx.x;
    const int blk = blockIdx.x;           // 768 blocks x 16 rows
    const int lane = t & 63;
    const int w = t >> 6;                 // wave -> 64-col block
    const int quad = lane >> 4;
    const int mrow = lane & 15;

    {
        int r = t >> 4;                   // 16 rows, 16 threads/row
        int ch = (t & 15) * 16;           // 16 floats each
        int rho = blk * 16 + r;
        int g = rho / NPG;
        int e = rho - g * NPG;
        const float* src = X + ((size_t)(g * EPG + e)) * DD + ch;
        ushort_t* dst = &sA[r * 272 + ch];
        #pragma unroll
        for (int i = 0; i < 2; ++i) {
            float4 v0 = *(const float4*)(src + i * 8);
            float4 v1 = *(const float4*)(src + i * 8 + 4);
            uint4 pk;
            pk.x = (uint_t)f2bf(v0.x) | ((uint_t)f2bf(v0.y) << 16);
            pk.y = (uint_t)f2bf(v0.z) | ((uint_t)f2bf(v0.w) << 16);
            pk.z = (uint_t)f2bf(v1.x) | ((uint_t)f2bf(v1.y) << 16);
            pk.w = (uint_t)f2bf(v1.z) | ((uint_t)f2bf(v1.w) << 16);
            *(uint4*)(dst + i * 8) = pk;
        }
    }
    __syncthreads();

    f32x4_t acc[4];
    #pragma unroll
    for (int i = 0; i < 4; ++i) acc[i] = (f32x4_t){0.f, 0.f, 0.f, 0.f};

    #pragma unroll
    for (int k0 = 0; k0 < 256; k0 += 32) {
        s16x8_t a = *(const s16x8_t*)&sA[mrow * 272 + k0 + quad * 8];
        #pragma unroll
        for (int nt = 0; nt < 4; ++nt) {
            s16x8_t bb = *(const s16x8_t*)(W1T + (size_t)(64 * w + nt * 16 + mrow) * 256 + k0 + quad * 8);
            acc[nt] = __builtin_amdgcn_mfma_f32_16x16x32_bf16(a, bb, acc[nt], 0, 0, 0);
        }
    }
    __syncthreads();

    #pragma unroll
    for (int nt = 0; nt < 4; ++nt) {
        int col = 64 * w + nt * 16 + mrow;
        float bias = b1[col];
        f32x4_t v = acc[nt];
        #pragma unroll
        for (int reg = 0; reg < 4; ++reg) {
            int row = quad * 4 + reg;
            sA[row * 272 + col] = f2bf(fmaxf(v[reg] + bias, 0.f));
        }
    }
    __syncthreads();

    #pragma unroll
    for (int i = 0; i < 4; ++i) acc[i] = (f32x4_t){0.f, 0.f, 0.f, 0.f};

    #pragma unroll
    for (int k0 = 0; k0 < 256; k0 += 32) {
        s16x8_t a = *(const s16x8_t*)&sA[mrow * 272 + k0 + quad * 8];
        #pragma unroll
        for (int nt = 0; nt < 4; ++nt) {
            s16x8_t bb = *(const s16x8_t*)(W2T + (size_t)(64 * w + nt * 16 + mrow) * 256 + k0 + quad * 8);
            acc[nt] = __builtin_amdgcn_mfma_f32_16x16x32_bf16(a, bb, acc[nt], 0, 0, 0);
        }
    }

    #pragma unroll
    for (int nt = 0; nt < 4; ++nt) {
        int col = 64 * w + nt * 16 + mrow;
        float bias = b2[col];
        f32x4_t v = acc[nt];
        #pragma unroll
        for (int reg = 0; reg < 4; ++reg) {
            int row = blk * 16 + quad * 4 + reg;
            Y[(size_t)row * 256 + col] = v[reg] + bias;
        }
    }
}

// ---------------------------------------------------------------------------
// Kernel C: per-b fused K-build -> 20x linear-domain Sinkhorn -> score.
// v6 = R7 (verified: 106 us, 18/26 MB) with ONE change:
//   row-step 16-lane butterfly moved from __shfl_xor (LDS pipe, ~5.8 cyc/op)
//   to DPP adds (VALU pipe) -- the LDS pipe is the saturated resource
//   (~56 us/CU of serialized shfl+ds traffic in the Sinkhorn loop).
// Col-step xor16/32 and the epilogue reduce stay shfl (not DPP-expressible /
// out of the hot loop). Structure (3 barriers/iter, LDS ru_s) unchanged.
// ---------------------------------------------------------------------------
__global__ __launch_bounds__(1024) void sink_kernel(
    const float* __restrict__ Tplan, const int* __restrict__ from_idx,
    const int* __restrict__ to_idx, const int* __restrict__ qsz,
    const int* __restrict__ csz, const float* __restrict__ qcf,
    float* __restrict__ out)
{
    const int b = blockIdx.x;
    const int t = threadIdx.x;
    const int R = t >> 4;      // row group: rows 4R..4R+3
    const int C = t & 15;      // col group: cols 16C..16C+15
    const int w = t >> 6;      // wave id (rows 16w..16w+15 live in wave w)

    // overlay region (phase-disjoint):
    //  build: Tl (33*33 f) @0, fq/tq/fc/tc @4368/5392/6416/7440
    //  iters: Vp [16][272] f @0 (17408 B)
    //  score: plan_s [256][25] f @0, cf_s @25600 ([24][16*20] swizzled)
    __shared__ __align__(16) char ovl[56320];
    __shared__ float ru_s[260];
    __shared__ float rv_p[320];    // col chunk C at rv_p[20C..20C+15] (b128-aligned)
    __shared__ float wsum[16];

    float* Tl = (float*)ovl;
    int* fq = (int*)(ovl + 4368);
    int* tq = (int*)(ovl + 5392);
    int* fc = (int*)(ovl + 6416);
    int* tc = (int*)(ovl + 7440);
    float* Vp = (float*)ovl;               // [16][272]
    float* plan_s = (float*)ovl;           // [256][25]
    float* cf_s   = (float*)(ovl + 25600);

    // --- phase 1: init ---
    for (int i = t; i < 33 * 33; i += 1024) Tl[i] = 0.f;
    if (t < 320) rv_p[t] = 1.0f;
    if (t < 256) {
        int gq = 2 * b, gc = 2 * b + 1;
        int a = NMAXI, bb = NMAXI, c = NMAXI, d = NMAXI;
        if (t < EPG) {
            a  = from_idx[gq * EPG + t] - gq * NPG;
            bb = to_idx  [gq * EPG + t] - gq * NPG;
            c  = from_idx[gc * EPG + t] - gc * NPG;
            d  = to_idx  [gc * EPG + t] - gc * NPG;
        }
        fq[t] = a; tq[t] = bb; fc[t] = c; tc[t] = d;
    }
    __syncthreads();
    {
        int i = t >> 5, j = t & 31;
        Tl[i * 33 + j] = Tplan[((size_t)b << 10) + t];
    }
    __syncthreads();

    // --- build K tile: Kp[i][u] packs cols (16C+2u, 16C+2u+1) of row 4R+i ---
    uint_t Kp[4][8];
    {
        int fcl[16], tcl[16];
        #pragma unroll
        for (int o = 0; o < 16; ++o) { fcl[o] = fc[16 * C + o]; tcl[o] = tc[16 * C + o]; }
        #pragma unroll
        for (int i = 0; i < 4; ++i) {
            const float* T1 = &Tl[fq[4 * R + i] * 33];
            const float* T2 = &Tl[tq[4 * R + i] * 33];
            #pragma unroll
            for (int u = 0; u < 8; ++u) {
                int f0 = fcl[2 * u], t0 = tcl[2 * u];
                int f1 = fcl[2 * u + 1], t1 = tcl[2 * u + 1];
                float la0 = T1[f0] * T2[t0] + T1[t0] * T2[f0];
                float la1 = T1[f1] * T2[t1] + T1[t1] * T2[f1];
                Kp[i][u] = (uint_t)f2bf(exp2f(la0 * L2E_OVER_T))
                         | ((uint_t)f2bf(exp2f(la1 * L2E_OVER_T)) << 16);
            }
        }
    }

    // --- 20 Sinkhorn iterations (3 barriers/iter, R7 structure) ---
    for (int it = 0; it < 20; ++it) {
        // row step: U_r = sum_j K[r][j] * rv[j]
        {
            float4 rv0 = *(const float4*)&rv_p[20 * C + 0];
            float4 rv1 = *(const float4*)&rv_p[20 * C + 4];
            float4 rv2 = *(const float4*)&rv_p[20 * C + 8];
            float4 rv3 = *(const float4*)&rv_p[20 * C + 12];
            float pr[4];
            #pragma unroll
            for (int i = 0; i < 4; ++i) {
                float a0 = bflo(Kp[i][0]) * rv0.x + bfhi(Kp[i][0]) * rv0.y;
                float a1 = bflo(Kp[i][1]) * rv0.z + bfhi(Kp[i][1]) * rv0.w;
                float a2 = bflo(Kp[i][2]) * rv1.x + bfhi(Kp[i][2]) * rv1.y;
                float a3 = bflo(Kp[i][3]) * rv1.z + bfhi(Kp[i][3]) * rv1.w;
                a0 += bflo(Kp[i][4]) * rv2.x + bfhi(Kp[i][4]) * rv2.y;
                a1 += bflo(Kp[i][5]) * rv2.z + bfhi(Kp[i][5]) * rv2.w;
                a2 += bflo(Kp[i][6]) * rv3.x + bfhi(Kp[i][6]) * rv3.y;
                a3 += bflo(Kp[i][7]) * rv3.z + bfhi(Kp[i][7]) * rv3.w;
                pr[i] = (a0 + a1) + (a2 + a3);
            }
            #pragma unroll
            for (int i = 0; i < 4; ++i)
                pr[i] = row16_reduce_dpp(pr[i]);   // VALU pipe, not LDS
            if (C == 0) {
                #pragma unroll
                for (int i = 0; i < 4; ++i) ru_s[4 * R + i] = frcp(pr[i]);
            }
        }
        __syncthreads();
        // col step: V_j = sum_i K[i][j] * ru[i]  (two pc[8] halves)
        {
            float u0 = ru_s[4 * R + 0], u1 = ru_s[4 * R + 1];
            float u2 = ru_s[4 * R + 2], u3 = ru_s[4 * R + 3];
            #pragma unroll
            for (int h = 0; h < 2; ++h) {
                float pc[8];
                #pragma unroll
                for (int u = 0; u < 4; ++u) {
                    int uu = 4 * h + u;
                    float e0 = bflo(Kp[0][uu]) * u0 + bflo(Kp[1][uu]) * u1
                             + bflo(Kp[2][uu]) * u2 + bflo(Kp[3][uu]) * u3;
                    float e1 = bfhi(Kp[0][uu]) * u0 + bfhi(Kp[1][uu]) * u1
                             + bfhi(Kp[2][uu]) * u2 + bfhi(Kp[3][uu]) * u3;
                    pc[2 * u] = e0; pc[2 * u + 1] = e1;
                }
                #pragma unroll
                for (int k = 0; k < 8; ++k) {
                    float s = pc[k];
                    s += __shfl_xor(s, 16);
                    s += __shfl_xor(s, 32);
                    pc[k] = s;
                }
                if ((t & 63) < 16) {   // one lane per C holds 16-row sums
                    float* dst = &Vp[w * 272 + C * 16 + 8 * h];
                    *(float4*)(dst + 0) = (float4){pc[0], pc[1], pc[2], pc[3]};
                    *(float4*)(dst + 4) = (float4){pc[4], pc[5], pc[6], pc[7]};
                }
            }
        }
        __syncthreads();
        if (t < 256) {   // second stage: sum the 16 wave partials
            float s = 0.f;
            #pragma unroll
            for (int ww = 0; ww < 16; ++ww) s += Vp[ww * 272 + t];
            rv_p[(t >> 4) * 20 + (t & 15)] = frcp(s);
        }
        __syncthreads();
    }

    // --- plan: plan_s[r][j] = K[r][j] * ru[r] * rv[j], j < 24 ---
    int nq = qsz[b]; if (nq > 24) nq = 24;
    int nc = csz[b]; if (nc > 24) nc = 24;

    if (C < 2) {
        int umax = (C == 0) ? 8 : 4;   // C=0: cols 0..15; C=1: cols 16..23
        #pragma unroll
        for (int i = 0; i < 4; ++i) {
            float rr = ru_s[4 * R + i];
            for (int u = 0; u < umax; ++u) {
                int j = 16 * C + 2 * u;
                plan_s[(4 * R + i) * 25 + j]     = bflo(Kp[i][u]) * rr * rv_p[20 * C + 2 * u];
                plan_s[(4 * R + i) * 25 + j + 1] = bfhi(Kp[i][u]) * rr * rv_p[20 * C + 2 * u + 1];
            }
        }
    }
    if (t < 768) {  // cf rows -> swizzled LDS chunks of 16 floats @ stride 20
        int j = t >> 5, inner = t & 31;
        int c = inner * 8;
        const float* src = qcf + ((size_t)(2 * b + 1) * 24 + j) * 256 + c;
        float4 v0 = *(const float4*)(src);
        float4 v1 = *(const float4*)(src + 4);
        float* dst = cf_s + j * 320 + (c >> 4) * 20 + (c & 15);
        *(float4*)dst = v0;
        *(float4*)(dst + 4) = v1;
    }
    __syncthreads();

    // --- score: thread = rows 4R..4R+3 x cols 16C..16C+15, 2 d-passes ---
    const int r0 = R * 4;
    const int m  = C;
    const float* qbase = qcf + (size_t)(2 * b) * 24 * 256;

    float ssum = 0.f;
    #pragma unroll
    for (int p = 0; p < 2; ++p) {
        float ps[32];
        #pragma unroll
        for (int i = 0; i < 32; ++i) ps[i] = 0.f;

        for (int j = 0; j < nc; ++j) {
            float p0 = plan_s[(r0 + 0) * 25 + j];
            float p1 = plan_s[(r0 + 1) * 25 + j];
            float p2 = plan_s[(r0 + 2) * 25 + j];
            float p3 = plan_s[(r0 + 3) * 25 + j];
            const float4* cfp = (const float4*)(cf_s + j * 320 + m * 20) + 2 * p;
            #pragma unroll
            for (int k = 0; k < 2; ++k) {
                float4 cv = cfp[k];
                ps[ 0 + k * 4 + 0] += p0 * cv.x; ps[ 0 + k * 4 + 1] += p0 * cv.y;
                ps[ 0 + k * 4 + 2] += p0 * cv.z; ps[ 0 + k * 4 + 3] += p0 * cv.w;
                ps[ 8 + k * 4 + 0] += p1 * cv.x; ps[ 8 + k * 4 + 1] += p1 * cv.y;
                ps[ 8 + k * 4 + 2] += p1 * cv.z; ps[ 8 + k * 4 + 3] += p1 * cv.w;
                ps[16 + k * 4 + 0] += p2 * cv.x; ps[16 + k * 4 + 1] += p2 * cv.y;
                ps[16 + k * 4 + 2] += p2 * cv.z; ps[16 + k * 4 + 3] += p2 * cv.w;
                ps[24 + k * 4 + 0] += p3 * cv.x; ps[24 + k * 4 + 1] += p3 * cv.y;
                ps[24 + k * 4 + 2] += p3 * cv.z; ps[24 + k * 4 + 3] += p3 * cv.w;
            }
        }

        #pragma unroll
        for (int i = 0; i < 4; ++i) {
            int row = r0 + i;
            if (row < nq) {
                const float4* qp = (const float4*)(qbase + (size_t)row * 256 + m * 16) + 2 * p;
                #pragma unroll
                for (int k = 0; k < 2; ++k) {
                    float4 qv = qp[k];
                    ssum += fmaxf(qv.x - ps[i * 8 + k * 4 + 0], 0.f);
                    ssum += fmaxf(qv.y - ps[i * 8 + k * 4 + 1], 0.f);
                    ssum += fmaxf(qv.z - ps[i * 8 + k * 4 + 2], 0.f);
                    ssum += fmaxf(qv.w - ps[i * 8 + k * 4 + 3], 0.f);
                }
            } else {
                #pragma unroll
                for (int k = 0; k < 8; ++k) ssum += fmaxf(-ps[i * 8 + k], 0.f);
            }
        }
    }

    ssum += __shfl_xor(ssum, 1);
    ssum += __shfl_xor(ssum, 2);
    ssum += __shfl_xor(ssum, 4);
    ssum += __shfl_xor(ssum, 8);
    ssum += __shfl_xor(ssum, 16);
    ssum += __shfl_xor(ssum, 32);
    if ((t & 63) == 0) wsum[t >> 6] = ssum;
    __syncthreads();
    if (t == 0) {
        float s = 0.f;
        #pragma unroll
        for (int i = 0; i < 16; ++i) s += wsum[i];
        out[b] = -s;
    }
}

// ---------------------------------------------------------------------------
extern "C" void kernel_launch(void* const* d_in, const int* in_sizes, int n_in,
                              void* d_out, int out_size, void* d_ws, size_t ws_size,
                              hipStream_t stream)
{
    const float* edge_feat = (const float*)d_in[0];
    const float* tplan     = (const float*)d_in[1];
    const float* W1        = (const float*)d_in[2];
    const float* b1        = (const float*)d_in[3];
    const float* W2        = (const float*)d_in[4];
    const float* b2        = (const float*)d_in[5];
    const int*   from_idx  = (const int*)d_in[6];
    const int*   to_idx    = (const int*)d_in[7];
    const int*   qsz       = (const int*)d_in[9];
    const int*   csz       = (const int*)d_in[10];
    float* out = (float*)d_out;

    // workspace: [0,128K) W1T bf16 | [128K,256K) W2T bf16 | [256K,+12.6MB) qcf f32
    char* ws = (char*)d_ws;
    ushort_t* W1T = (ushort_t*)ws;
    ushort_t* W2T = W1T + 65536;
    float* qcf = (float*)(ws + 262144);

    prep_w<<<64, 256, 0, stream>>>(W1, W2, W1T, W2T);
    mlp_kernel<<<768, 256, 0, stream>>>(edge_feat, W1T, W2T, b1, b2, qcf);
    sink_kernel<<<256, 1024, 0, stream>>>(tplan, from_idx, to_idx, qsz, csz, qcf, out);
}

// Round 9
// 263.134 us; speedup vs baseline: 1.5702x; 1.0089x over previous
//
#include <hip/hip_runtime.h>

typedef unsigned short ushort_t;
typedef unsigned int uint_t;

typedef float f32x4_t __attribute__((ext_vector_type(4)));
typedef short s16x8_t __attribute__((ext_vector_type(8)));

#define NB   256   // B
#define NG   512   // 2*B graphs
#define NPG  24    // nodes per graph
#define NMAXI 32   // N_MAX
#define EPG  200   // edges per graph
#define DD   256   // feature dim
// 1/TEMPERATURE * log2(e) = 10 * 1.4426950408889634
#define L2E_OVER_T 14.426950408889634f

__device__ __forceinline__ ushort_t f2bf(float f) {
    uint_t u = __float_as_uint(f);
    u += 0x7FFFu + ((u >> 16) & 1u);        // round-to-nearest-even
    return (ushort_t)(u >> 16);
}
__device__ __forceinline__ float bfhi(uint_t u) { return __uint_as_float(u & 0xFFFF0000u); }
__device__ __forceinline__ float bflo(uint_t u) { return __uint_as_float(u << 16); }

__device__ __forceinline__ float frcp(float x) {
#if __has_builtin(__builtin_amdgcn_rcpf)
    return __builtin_amdgcn_rcpf(x);
#else
    return 1.0f / x;
#endif
}

// ---- DPP 16-lane reduction on the VALU pipe (HW-verified in R8) ----------
template <int CTRL>
__device__ __forceinline__ float dpp_radd(float s) {
    int d = __builtin_amdgcn_update_dpp(0, __float_as_int(s), CTRL, 0xF, 0xF, true);
    return s + __int_as_float(d);
}
__device__ __forceinline__ float row16_reduce_dpp(float s) {
    s = dpp_radd<0xB1>(s);   // quad_perm [1,0,3,2]  (xor 1)
    s = dpp_radd<0x4E>(s);   // quad_perm [2,3,0,1]  (xor 2)
    s = dpp_radd<0x141>(s);  // row_half_mirror      (xor 4 equiv)
    s = dpp_radd<0x140>(s);  // row_mirror           (xor 8 equiv)
    return s;   // all 16 lanes of the group hold the sum
}

// ---------------------------------------------------------------------------
// Kernel A: W1,W2 -> bf16 transposed ([n][k]), via LDS transpose.
// ---------------------------------------------------------------------------
__global__ __launch_bounds__(256) void prep_w(const float* __restrict__ W1,
                                              const float* __restrict__ W2,
                                              ushort_t* __restrict__ W1T,
                                              ushort_t* __restrict__ W2T)
{
    __shared__ float tile[2][4 * 256];
    const int t = threadIdx.x;
    const int k0 = blockIdx.x * 4;
    #pragma unroll
    for (int i = t; i < 4 * 256; i += 256) {
        tile[0][i] = W1[k0 * 256 + i];
        tile[1][i] = W2[k0 * 256 + i];
    }
    __syncthreads();
    const int n = t;
    #pragma unroll
    for (int m = 0; m < 2; ++m) {
        uint_t p0 = (uint_t)f2bf(tile[m][0 * 256 + n]) | ((uint_t)f2bf(tile[m][1 * 256 + n]) << 16);
        uint_t p1 = (uint_t)f2bf(tile[m][2 * 256 + n]) | ((uint_t)f2bf(tile[m][3 * 256 + n]) << 16);
        ushort_t* dst = (m ? W2T : W1T) + n * 256 + k0;
        uint2 pk; pk.x = p0; pk.y = p1;
        *(uint2*)dst = pk;
    }
}

// ---------------------------------------------------------------------------
// Kernel B: fused 2-layer MLP on the 12288 surviving edge rows (rank < 24).
// 768 blocks x 16 rows (verified correct R4-R8).
// ---------------------------------------------------------------------------
__global__ __launch_bounds__(256) void mlp_kernel(
    const float* __restrict__ X, const ushort_t* __restrict__ W1T,
    const ushort_t* __restrict__ W2T, const float* __restrict__ b1,
    const float* __restrict__ b2, float* __restrict__ Y)
{
    __shared__ ushort_t sA[16 * 272];
    const int t = threadIdx.x;
    const int blk = blockIdx.x;           // 768 blocks x 16 rows
    const int lane = t & 63;
    const int w = t >> 6;                 // wave -> 64-col block
    const int quad = lane >> 4;
    const int mrow = lane & 15;

    {
        int r = t >> 4;                   // 16 rows, 16 threads/row
        int ch = (t & 15) * 16;           // 16 floats each
        int rho = blk * 16 + r;
        int g = rho / NPG;
        int e = rho - g * NPG;
        const float* src = X + ((size_t)(g * EPG + e)) * DD + ch;
        ushort_t* dst = &sA[r * 272 + ch];
        #pragma unroll
        for (int i = 0; i < 2; ++i) {
            float4 v0 = *(const float4*)(src + i * 8);
            float4 v1 = *(const float4*)(src + i * 8 + 4);
            uint4 pk;
            pk.x = (uint_t)f2bf(v0.x) | ((uint_t)f2bf(v0.y) << 16);
            pk.y = (uint_t)f2bf(v0.z) | ((uint_t)f2bf(v0.w) << 16);
            pk.z = (uint_t)f2bf(v1.x) | ((uint_t)f2bf(v1.y) << 16);
            pk.w = (uint_t)f2bf(v1.z) | ((uint_t)f2bf(v1.w) << 16);
            *(uint4*)(dst + i * 8) = pk;
        }
    }
    __syncthreads();

    f32x4_t acc[4];
    #pragma unroll
    for (int i = 0; i < 4; ++i) acc[i] = (f32x4_t){0.f, 0.f, 0.f, 0.f};

    #pragma unroll
    for (int k0 = 0; k0 < 256; k0 += 32) {
        s16x8_t a = *(const s16x8_t*)&sA[mrow * 272 + k0 + quad * 8];
        #pragma unroll
        for (int nt = 0; nt < 4; ++nt) {
            s16x8_t bb = *(const s16x8_t*)(W1T + (size_t)(64 * w + nt * 16 + mrow) * 256 + k0 + quad * 8);
            acc[nt] = __builtin_amdgcn_mfma_f32_16x16x32_bf16(a, bb, acc[nt], 0, 0, 0);
        }
    }
    __syncthreads();

    #pragma unroll
    for (int nt = 0; nt < 4; ++nt) {
        int col = 64 * w + nt * 16 + mrow;
        float bias = b1[col];
        f32x4_t v = acc[nt];
        #pragma unroll
        for (int reg = 0; reg < 4; ++reg) {
            int row = quad * 4 + reg;
            sA[row * 272 + col] = f2bf(fmaxf(v[reg] + bias, 0.f));
        }
    }
    __syncthreads();

    #pragma unroll
    for (int i = 0; i < 4; ++i) acc[i] = (f32x4_t){0.f, 0.f, 0.f, 0.f};

    #pragma unroll
    for (int k0 = 0; k0 < 256; k0 += 32) {
        s16x8_t a = *(const s16x8_t*)&sA[mrow * 272 + k0 + quad * 8];
        #pragma unroll
        for (int nt = 0; nt < 4; ++nt) {
            s16x8_t bb = *(const s16x8_t*)(W2T + (size_t)(64 * w + nt * 16 + mrow) * 256 + k0 + quad * 8);
            acc[nt] = __builtin_amdgcn_mfma_f32_16x16x32_bf16(a, bb, acc[nt], 0, 0, 0);
        }
    }

    #pragma unroll
    for (int nt = 0; nt < 4; ++nt) {
        int col = 64 * w + nt * 16 + mrow;
        float bias = b2[col];
        f32x4_t v = acc[nt];
        #pragma unroll
        for (int reg = 0; reg < 4; ++reg) {
            int row = blk * 16 + quad * 4 + reg;
            Y[(size_t)row * 256 + col] = v[reg] + bias;
        }
    }
}

// ---------------------------------------------------------------------------
// Kernel C: per-b fused K-build -> 20x linear-domain Sinkhorn -> score.
// v7 = R8 with ONE structural change:
//   The DPP row-reduce already leaves pr[0..3] (row sums) in EVERY lane, so
//   the col step uses iteration-local uu[i] = frcp(pr[i]) directly:
//   barrier #1 and the per-iter ru_s LDS reads are deleted (2 barriers/iter).
//   ru_s is still written (C==0) each iter, but only the plan phase reads it
//   (after the loop's final barrier - no race).
//   NOTE vs R4's failed variant: uu is DEAD at each loop back-edge (pr/uu are
//   rewritten before any use in the next iteration) and ru_s serves the plan
//   phase - no loop-crossing register liveness -> no spill (R4 kept u_r live
//   across the loop into the plan phase: 580 MB spill traffic).
// ---------------------------------------------------------------------------
__global__ __launch_bounds__(1024) void sink_kernel(
    const float* __restrict__ Tplan, const int* __restrict__ from_idx,
    const int* __restrict__ to_idx, const int* __restrict__ qsz,
    const int* __restrict__ csz, const float* __restrict__ qcf,
    float* __restrict__ out)
{
    const int b = blockIdx.x;
    const int t = threadIdx.x;
    const int R = t >> 4;      // row group: rows 4R..4R+3
    const int C = t & 15;      // col group: cols 16C..16C+15
    const int w = t >> 6;      // wave id (rows 16w..16w+15 live in wave w)

    // overlay region (phase-disjoint):
    //  build: Tl (33*33 f) @0, fq/tq/fc/tc @4368/5392/6416/7440
    //  iters: Vp [16][272] f @0 (17408 B)
    //  score: plan_s [256][25] f @0, cf_s @25600 ([24][16*20] swizzled)
    __shared__ __align__(16) char ovl[56320];
    __shared__ float ru_s[260];
    __shared__ float rv_p[320];    // col chunk C at rv_p[20C..20C+15] (b128-aligned)
    __shared__ float wsum[16];

    float* Tl = (float*)ovl;
    int* fq = (int*)(ovl + 4368);
    int* tq = (int*)(ovl + 5392);
    int* fc = (int*)(ovl + 6416);
    int* tc = (int*)(ovl + 7440);
    float* Vp = (float*)ovl;               // [16][272]
    float* plan_s = (float*)ovl;           // [256][25]
    float* cf_s   = (float*)(ovl + 25600);

    // --- phase 1: init ---
    for (int i = t; i < 33 * 33; i += 1024) Tl[i] = 0.f;
    if (t < 320) rv_p[t] = 1.0f;
    if (t < 256) {
        int gq = 2 * b, gc = 2 * b + 1;
        int a = NMAXI, bb = NMAXI, c = NMAXI, d = NMAXI;
        if (t < EPG) {
            a  = from_idx[gq * EPG + t] - gq * NPG;
            bb = to_idx  [gq * EPG + t] - gq * NPG;
            c  = from_idx[gc * EPG + t] - gc * NPG;
            d  = to_idx  [gc * EPG + t] - gc * NPG;
        }
        fq[t] = a; tq[t] = bb; fc[t] = c; tc[t] = d;
    }
    __syncthreads();
    {
        int i = t >> 5, j = t & 31;
        Tl[i * 33 + j] = Tplan[((size_t)b << 10) + t];
    }
    __syncthreads();

    // --- build K tile: Kp[i][u] packs cols (16C+2u, 16C+2u+1) of row 4R+i ---
    uint_t Kp[4][8];
    {
        int fcl[16], tcl[16];
        #pragma unroll
        for (int o = 0; o < 16; ++o) { fcl[o] = fc[16 * C + o]; tcl[o] = tc[16 * C + o]; }
        #pragma unroll
        for (int i = 0; i < 4; ++i) {
            const float* T1 = &Tl[fq[4 * R + i] * 33];
            const float* T2 = &Tl[tq[4 * R + i] * 33];
            #pragma unroll
            for (int u = 0; u < 8; ++u) {
                int f0 = fcl[2 * u], t0 = tcl[2 * u];
                int f1 = fcl[2 * u + 1], t1 = tcl[2 * u + 1];
                float la0 = T1[f0] * T2[t0] + T1[t0] * T2[f0];
                float la1 = T1[f1] * T2[t1] + T1[t1] * T2[f1];
                Kp[i][u] = (uint_t)f2bf(exp2f(la0 * L2E_OVER_T))
                         | ((uint_t)f2bf(exp2f(la1 * L2E_OVER_T)) << 16);
            }
        }
    }

    // --- 20 Sinkhorn iterations (2 barriers/iter) ---
    for (int it = 0; it < 20; ++it) {
        // row step: pr = K * rv row sums (DPP broadcast to all lanes),
        // uu = 1/pr used directly by the col step (iteration-local).
        float uu[4];
        {
            float4 rv0 = *(const float4*)&rv_p[20 * C + 0];
            float4 rv1 = *(const float4*)&rv_p[20 * C + 4];
            float4 rv2 = *(const float4*)&rv_p[20 * C + 8];
            float4 rv3 = *(const float4*)&rv_p[20 * C + 12];
            #pragma unroll
            for (int i = 0; i < 4; ++i) {
                float a0 = bflo(Kp[i][0]) * rv0.x + bfhi(Kp[i][0]) * rv0.y;
                float a1 = bflo(Kp[i][1]) * rv0.z + bfhi(Kp[i][1]) * rv0.w;
                float a2 = bflo(Kp[i][2]) * rv1.x + bfhi(Kp[i][2]) * rv1.y;
                float a3 = bflo(Kp[i][3]) * rv1.z + bfhi(Kp[i][3]) * rv1.w;
                a0 += bflo(Kp[i][4]) * rv2.x + bfhi(Kp[i][4]) * rv2.y;
                a1 += bflo(Kp[i][5]) * rv2.z + bfhi(Kp[i][5]) * rv2.w;
                a2 += bflo(Kp[i][6]) * rv3.x + bfhi(Kp[i][6]) * rv3.y;
                a3 += bflo(Kp[i][7]) * rv3.z + bfhi(Kp[i][7]) * rv3.w;
                float s = (a0 + a1) + (a2 + a3);
                s = row16_reduce_dpp(s);    // VALU pipe; all 16 lanes hold sum
                uu[i] = frcp(s);
            }
            if (C == 0) {   // ru_s only consumed by the plan phase post-loop
                #pragma unroll
                for (int i = 0; i < 4; ++i) ru_s[4 * R + i] = uu[i];
            }
        }
        // col step: V_j = sum_i K[i][j] * uu[i]  (two pc[8] halves)
        {
            #pragma unroll
            for (int h = 0; h < 2; ++h) {
                float pc[8];
                #pragma unroll
                for (int u = 0; u < 4; ++u) {
                    int uu_i = 4 * h + u;
                    float e0 = bflo(Kp[0][uu_i]) * uu[0] + bflo(Kp[1][uu_i]) * uu[1]
                             + bflo(Kp[2][uu_i]) * uu[2] + bflo(Kp[3][uu_i]) * uu[3];
                    float e1 = bfhi(Kp[0][uu_i]) * uu[0] + bfhi(Kp[1][uu_i]) * uu[1]
                             + bfhi(Kp[2][uu_i]) * uu[2] + bfhi(Kp[3][uu_i]) * uu[3];
                    pc[2 * u] = e0; pc[2 * u + 1] = e1;
                }
                #pragma unroll
                for (int k = 0; k < 8; ++k) {
                    float s = pc[k];
                    s += __shfl_xor(s, 16);
                    s += __shfl_xor(s, 32);
                    pc[k] = s;
                }
                if ((t & 63) < 16) {   // one lane per C holds 16-row sums
                    float* dst = &Vp[w * 272 + C * 16 + 8 * h];
                    *(float4*)(dst + 0) = (float4){pc[0], pc[1], pc[2], pc[3]};
                    *(float4*)(dst + 4) = (float4){pc[4], pc[5], pc[6], pc[7]};
                }
            }
        }
        __syncthreads();
        if (t < 256) {   // second stage: sum the 16 wave partials
            float s = 0.f;
            #pragma unroll
            for (int ww = 0; ww < 16; ++ww) s += Vp[ww * 272 + t];
            rv_p[(t >> 4) * 20 + (t & 15)] = frcp(s);
        }
        __syncthreads();
    }

    // --- plan: plan_s[r][j] = K[r][j] * ru[r] * rv[j], j < 24 ---
    int nq = qsz[b]; if (nq > 24) nq = 24;
    int nc = csz[b]; if (nc > 24) nc = 24;

    if (C < 2) {
        int umax = (C == 0) ? 8 : 4;   // C=0: cols 0..15; C=1: cols 16..23
        #pragma unroll
        for (int i = 0; i < 4; ++i) {
            float rr = ru_s[4 * R + i];
            for (int u = 0; u < umax; ++u) {
                int j = 16 * C + 2 * u;
                plan_s[(4 * R + i) * 25 + j]     = bflo(Kp[i][u]) * rr * rv_p[20 * C + 2 * u];
                plan_s[(4 * R + i) * 25 + j + 1] = bfhi(Kp[i][u]) * rr * rv_p[20 * C + 2 * u + 1];
            }
        }
    }
    if (t < 768) {  // cf rows -> swizzled LDS chunks of 16 floats @ stride 20
        int j = t >> 5, inner = t & 31;
        int c = inner * 8;
        const float* src = qcf + ((size_t)(2 * b + 1) * 24 + j) * 256 + c;
        float4 v0 = *(const float4*)(src);
        float4 v1 = *(const float4*)(src + 4);
        float* dst = cf_s + j * 320 + (c >> 4) * 20 + (c & 15);
        *(float4*)dst = v0;
        *(float4*)(dst + 4) = v1;
    }
    __syncthreads();

    // --- score: thread = rows 4R..4R+3 x cols 16C..16C+15, 2 d-passes ---
    const int r0 = R * 4;
    const int m  = C;
    const float* qbase = qcf + (size_t)(2 * b) * 24 * 256;

    float ssum = 0.f;
    #pragma unroll
    for (int p = 0; p < 2; ++p) {
        float ps[32];
        #pragma unroll
        for (int i = 0; i < 32; ++i) ps[i] = 0.f;

        for (int j = 0; j < nc; ++j) {
            float p0 = plan_s[(r0 + 0) * 25 + j];
            float p1 = plan_s[(r0 + 1) * 25 + j];
            float p2 = plan_s[(r0 + 2) * 25 + j];
            float p3 = plan_s[(r0 + 3) * 25 + j];
            const float4* cfp = (const float4*)(cf_s + j * 320 + m * 20) + 2 * p;
            #pragma unroll
            for (int k = 0; k < 2; ++k) {
                float4 cv = cfp[k];
                ps[ 0 + k * 4 + 0] += p0 * cv.x; ps[ 0 + k * 4 + 1] += p0 * cv.y;
                ps[ 0 + k * 4 + 2] += p0 * cv.z; ps[ 0 + k * 4 + 3] += p0 * cv.w;
                ps[ 8 + k * 4 + 0] += p1 * cv.x; ps[ 8 + k * 4 + 1] += p1 * cv.y;
                ps[ 8 + k * 4 + 2] += p1 * cv.z; ps[ 8 + k * 4 + 3] += p1 * cv.w;
                ps[16 + k * 4 + 0] += p2 * cv.x; ps[16 + k * 4 + 1] += p2 * cv.y;
                ps[16 + k * 4 + 2] += p2 * cv.z; ps[16 + k * 4 + 3] += p2 * cv.w;
                ps[24 + k * 4 + 0] += p3 * cv.x; ps[24 + k * 4 + 1] += p3 * cv.y;
                ps[24 + k * 4 + 2] += p3 * cv.z; ps[24 + k * 4 + 3] += p3 * cv.w;
            }
        }

        #pragma unroll
        for (int i = 0; i < 4; ++i) {
            int row = r0 + i;
            if (row < nq) {
                const float4* qp = (const float4*)(qbase + (size_t)row * 256 + m * 16) + 2 * p;
                #pragma unroll
                for (int k = 0; k < 2; ++k) {
                    float4 qv = qp[k];
                    ssum += fmaxf(qv.x - ps[i * 8 + k * 4 + 0], 0.f);
                    ssum += fmaxf(qv.y - ps[i * 8 + k * 4 + 1], 0.f);
                    ssum += fmaxf(qv.z - ps[i * 8 + k * 4 + 2], 0.f);
                    ssum += fmaxf(qv.w - ps[i * 8 + k * 4 + 3], 0.f);
                }
            } else {
                #pragma unroll
                for (int k = 0; k < 8; ++k) ssum += fmaxf(-ps[i * 8 + k], 0.f);
            }
        }
    }

    ssum += __shfl_xor(ssum, 1);
    ssum += __shfl_xor(ssum, 2);
    ssum += __shfl_xor(ssum, 4);
    ssum += __shfl_xor(ssum, 8);
    ssum += __shfl_xor(ssum, 16);
    ssum += __shfl_xor(ssum, 32);
    if ((t & 63) == 0) wsum[t >> 6] = ssum;
    __syncthreads();
    if (t == 0) {
        float s = 0.f;
        #pragma unroll
        for (int i = 0; i < 16; ++i) s += wsum[i];
        out[b] = -s;
    }
}

// ---------------------------------------------------------------------------
extern "C" void kernel_launch(void* const* d_in, const int* in_sizes, int n_in,
                              void* d_out, int out_size, void* d_ws, size_t ws_size,
                              hipStream_t stream)
{
    const float* edge_feat = (const float*)d_in[0];
    const float* tplan     = (const float*)d_in[1];
    const float* W1        = (const float*)d_in[2];
    const float* b1        = (const float*)d_in[3];
    const float* W2        = (const float*)d_in[4];
    const float* b2        = (const float*)d_in[5];
    const int*   from_idx  = (const int*)d_in[6];
    const int*   to_idx    = (const int*)d_in[7];
    const int*   qsz       = (const int*)d_in[9];
    const int*   csz       = (const int*)d_in[10];
    float* out = (float*)d_out;

    // workspace: [0,128K) W1T bf16 | [128K,256K) W2T bf16 | [256K,+12.6MB) qcf f32
    char* ws = (char*)d_ws;
    ushort_t* W1T = (ushort_t*)ws;
    ushort_t* W2T = W1T + 65536;
    float* qcf = (float*)(ws + 262144);

    prep_w<<<64, 256, 0, stream>>>(W1, W2, W1T, W2T);
    mlp_kernel<<<768, 256, 0, stream>>>(edge_feat, W1T, W2T, b1, b2, qcf);
    sink_kernel<<<256, 1024, 0, stream>>>(tplan, from_idx, to_idx, qsz, csz, qcf, out);
}

// Round 12
// 258.597 us; speedup vs baseline: 1.5978x; 1.0175x over previous
//
#include <hip/hip_runtime.h>

typedef unsigned short ushort_t;
typedef unsigned int uint_t;

typedef float f32x4_t __attribute__((ext_vector_type(4)));
typedef short s16x8_t __attribute__((ext_vector_type(8)));

#define NB   256   // B
#define NG   512   // 2*B graphs
#define NPG  24    // nodes per graph
#define NMAXI 32   // N_MAX
#define EPG  200   // edges per graph
#define DD   256   // feature dim
// 1/TEMPERATURE * log2(e) = 10 * 1.4426950408889634
#define L2E_OVER_T 14.426950408889634f

__device__ __forceinline__ ushort_t f2bf(float f) {
    uint_t u = __float_as_uint(f);
    u += 0x7FFFu + ((u >> 16) & 1u);        // round-to-nearest-even
    return (ushort_t)(u >> 16);
}
__device__ __forceinline__ float bfhi(uint_t u) { return __uint_as_float(u & 0xFFFF0000u); }
__device__ __forceinline__ float bflo(uint_t u) { return __uint_as_float(u << 16); }

__device__ __forceinline__ float frcp(float x) {
#if __has_builtin(__builtin_amdgcn_rcpf)
    return __builtin_amdgcn_rcpf(x);
#else
    return 1.0f / x;
#endif
}

// ---- DPP 16-lane reduction on the VALU pipe (HW-verified in R8) ----------
template <int CTRL>
__device__ __forceinline__ float dpp_radd(float s) {
    int d = __builtin_amdgcn_update_dpp(0, __float_as_int(s), CTRL, 0xF, 0xF, true);
    return s + __int_as_float(d);
}
__device__ __forceinline__ float row16_reduce_dpp(float s) {
    s = dpp_radd<0xB1>(s);   // quad_perm [1,0,3,2]  (xor 1)
    s = dpp_radd<0x4E>(s);   // quad_perm [2,3,0,1]  (xor 2)
    s = dpp_radd<0x141>(s);  // row_half_mirror      (xor 4 equiv)
    s = dpp_radd<0x140>(s);  // row_mirror           (xor 8 equiv)
    return s;   // all 16 lanes of the group hold the sum
}

// ---------------------------------------------------------------------------
// Kernel A: W1,W2 -> bf16 transposed ([n][k]), via LDS transpose.
// ---------------------------------------------------------------------------
__global__ __launch_bounds__(256) void prep_w(const float* __restrict__ W1,
                                              const float* __restrict__ W2,
                                              ushort_t* __restrict__ W1T,
                                              ushort_t* __restrict__ W2T)
{
    __shared__ float tile[2][4 * 256];
    const int t = threadIdx.x;
    const int k0 = blockIdx.x * 4;
    #pragma unroll
    for (int i = t; i < 4 * 256; i += 256) {
        tile[0][i] = W1[k0 * 256 + i];
        tile[1][i] = W2[k0 * 256 + i];
    }
    __syncthreads();
    const int n = t;
    #pragma unroll
    for (int m = 0; m < 2; ++m) {
        uint_t p0 = (uint_t)f2bf(tile[m][0 * 256 + n]) | ((uint_t)f2bf(tile[m][1 * 256 + n]) << 16);
        uint_t p1 = (uint_t)f2bf(tile[m][2 * 256 + n]) | ((uint_t)f2bf(tile[m][3 * 256 + n]) << 16);
        ushort_t* dst = (m ? W2T : W1T) + n * 256 + k0;
        uint2 pk; pk.x = p0; pk.y = p1;
        *(uint2*)dst = pk;
    }
}

// ---------------------------------------------------------------------------
// Kernel C (fused): per-b MLP(48 rows) -> K-build -> 20x Sinkhorn -> score.
// v8 = R9 + the standalone mlp_kernel folded in:
//   Each block needs exactly 48 MLP rows (graphs 2b,2b+1). 12 of the 16 waves
//   compute the two-layer MLP with the EXACT fragment pattern proven in
//   mlp_kernel (R4-R9); layer-2 epilogue writes straight into the swizzled
//   LDS layout the score phase reads (cf_s pattern) -> the mlp dispatch, its
//   launch gap, the 12.6MB qcf HBM round-trip, and sink's cf staging pass
//   are all deleted. LDS: 117 KB of the 160 KB/CU (grid = 1 block/CU).
//   Also: new __syncthreads() after K-build (closes the Vp-write/Tl-read
//   race carried since R0).
// ---------------------------------------------------------------------------
__global__ __launch_bounds__(1024) void sink_kernel(
    const float* __restrict__ Tplan, const float* __restrict__ X,
    const ushort_t* __restrict__ W1T, const ushort_t* __restrict__ W2T,
    const float* __restrict__ b1, const float* __restrict__ b2,
    const int* __restrict__ from_idx, const int* __restrict__ to_idx,
    const int* __restrict__ qsz, const int* __restrict__ csz,
    float* __restrict__ out)
{
    const int b = blockIdx.x;
    const int t = threadIdx.x;
    const int R = t >> 4;      // row group: rows 4R..4R+3
    const int C = t & 15;      // col group: cols 16C..16C+15
    const int w = t >> 6;      // wave id
    const int lane = t & 63;
    const int quad = lane >> 4;
    const int mrow = lane & 15;

    // overlay region (phase-disjoint):
    //  MLP:   xa bf16[48][272] @0 (26112) | h1 bf16[48][272] @26112 | qc f32 swizzled [48][320] @52224 (61440)
    //  build: Tl (33*33 f) @0
    //  iters: Vp [16][272] f @0 (17408 B)
    //  plan:  plan_s [256][25] f @0 (25600 B)
    //  qc persists @52224 until score.
    __shared__ __align__(16) char ovl[113664];
    __shared__ int fq_s[256], tq_s[256], fc_s[256], tc_s[256];
    __shared__ float ru_s[260];
    __shared__ float rv_p[320];    // col chunk C at rv_p[20C..20C+15]
    __shared__ float wsum[16];

    ushort_t* xa = (ushort_t*)ovl;              // [48][272] bf16
    ushort_t* h1 = (ushort_t*)(ovl + 26112);    // [48][272] bf16
    float*    qc = (float*)(ovl + 52224);       // [48][320] f32 swizzled chunks
    float* Tl = (float*)ovl;
    float* Vp = (float*)ovl;                    // [16][272]
    float* plan_s = (float*)ovl;                // [256][25]

    // --- phase 0: indices + rv_p init + X staging (48 rows -> xa bf16) ---
    if (t < 320) rv_p[t] = 1.0f;
    if (t < 256) {
        int gq = 2 * b, gc = 2 * b + 1;
        int a = NMAXI, bb = NMAXI, c = NMAXI, d = NMAXI;
        if (t < EPG) {
            a  = from_idx[gq * EPG + t] - gq * NPG;
            bb = to_idx  [gq * EPG + t] - gq * NPG;
            c  = from_idx[gc * EPG + t] - gc * NPG;
            d  = to_idx  [gc * EPG + t] - gc * NPG;
        }
        fq_s[t] = a; tq_s[t] = bb; fc_s[t] = c; tc_s[t] = d;
    }
    {
        int r = t >> 4;                   // 64 row slots, 48 used
        if (r < 48) {
            int half = (r >= 24);
            int g = 2 * b + half;
            int e = r - 24 * half;
            int ch = (t & 15) * 16;
            const float* src = X + ((size_t)(g * EPG + e)) * DD + ch;
            ushort_t* dst = &xa[r * 272 + ch];
            #pragma unroll
            for (int i = 0; i < 2; ++i) {
                float4 v0 = *(const float4*)(src + i * 8);
                float4 v1 = *(const float4*)(src + i * 8 + 4);
                uint4 pk;
                pk.x = (uint_t)f2bf(v0.x) | ((uint_t)f2bf(v0.y) << 16);
                pk.y = (uint_t)f2bf(v0.z) | ((uint_t)f2bf(v0.w) << 16);
                pk.z = (uint_t)f2bf(v1.x) | ((uint_t)f2bf(v1.y) << 16);
                pk.w = (uint_t)f2bf(v1.z) | ((uint_t)f2bf(v1.w) << 16);
                *(uint4*)(dst + i * 8) = pk;
            }
        }
    }
    __syncthreads();

    // --- MLP layer 1: wave (rc,cc) -> rows rc*16..+15, cols 64cc..+63 ---
    const int rc = w >> 2;     // 0..3 (3 = idle)
    const int cc = w & 3;
    if (rc < 3) {
        f32x4_t acc[4];
        #pragma unroll
        for (int i = 0; i < 4; ++i) acc[i] = (f32x4_t){0.f, 0.f, 0.f, 0.f};
        #pragma unroll
        for (int k0 = 0; k0 < 256; k0 += 32) {
            s16x8_t a = *(const s16x8_t*)&xa[(rc * 16 + mrow) * 272 + k0 + quad * 8];
            #pragma unroll
            for (int nt = 0; nt < 4; ++nt) {
                s16x8_t bb = *(const s16x8_t*)(W1T + (size_t)(64 * cc + nt * 16 + mrow) * 256 + k0 + quad * 8);
                acc[nt] = __builtin_amdgcn_mfma_f32_16x16x32_bf16(a, bb, acc[nt], 0, 0, 0);
            }
        }
        #pragma unroll
        for (int nt = 0; nt < 4; ++nt) {
            int col = 64 * cc + nt * 16 + mrow;
            float bias = b1[col];
            f32x4_t v = acc[nt];
            #pragma unroll
            for (int reg = 0; reg < 4; ++reg) {
                int row = rc * 16 + quad * 4 + reg;
                h1[row * 272 + col] = f2bf(fmaxf(v[reg] + bias, 0.f));
            }
        }
    }
    __syncthreads();

    // --- MLP layer 2: h1 @ W2T + b2 -> qc (f32, swizzled 16-float chunks) ---
    if (rc < 3) {
        f32x4_t acc[4];
        #pragma unroll
        for (int i = 0; i < 4; ++i) acc[i] = (f32x4_t){0.f, 0.f, 0.f, 0.f};
        #pragma unroll
        for (int k0 = 0; k0 < 256; k0 += 32) {
            s16x8_t a = *(const s16x8_t*)&h1[(rc * 16 + mrow) * 272 + k0 + quad * 8];
            #pragma unroll
            for (int nt = 0; nt < 4; ++nt) {
                s16x8_t bb = *(const s16x8_t*)(W2T + (size_t)(64 * cc + nt * 16 + mrow) * 256 + k0 + quad * 8);
                acc[nt] = __builtin_amdgcn_mfma_f32_16x16x32_bf16(a, bb, acc[nt], 0, 0, 0);
            }
        }
        #pragma unroll
        for (int nt = 0; nt < 4; ++nt) {
            int col = 64 * cc + nt * 16 + mrow;   // col>>4 = 4cc+nt, col&15 = mrow
            float bias = b2[col];
            f32x4_t v = acc[nt];
            #pragma unroll
            for (int reg = 0; reg < 4; ++reg) {
                int row = rc * 16 + quad * 4 + reg;
                qc[row * 320 + (4 * cc + nt) * 20 + mrow] = v[reg] + bias;
            }
        }
    }
    __syncthreads();   // xa/h1 dead; qc complete (persists to score)

    // --- load T (zero-pad to 33x33) ---
    for (int i = t; i < 33 * 33; i += 1024) Tl[i] = 0.f;
    __syncthreads();
    {
        int i = t >> 5, j = t & 31;
        Tl[i * 33 + j] = Tplan[((size_t)b << 10) + t];
    }
    __syncthreads();

    // --- build K tile: Kp[i][u] packs cols (16C+2u, 16C+2u+1) of row 4R+i ---
    uint_t Kp[4][8];
    {
        int fcl[16], tcl[16];
        #pragma unroll
        for (int o = 0; o < 16; ++o) { fcl[o] = fc_s[16 * C + o]; tcl[o] = tc_s[16 * C + o]; }
        #pragma unroll
        for (int i = 0; i < 4; ++i) {
            const float* T1 = &Tl[fq_s[4 * R + i] * 33];
            const float* T2 = &Tl[tq_s[4 * R + i] * 33];
            #pragma unroll
            for (int u = 0; u < 8; ++u) {
                int f0 = fcl[2 * u], t0 = tcl[2 * u];
                int f1 = fcl[2 * u + 1], t1 = tcl[2 * u + 1];
                float la0 = T1[f0] * T2[t0] + T1[t0] * T2[f0];
                float la1 = T1[f1] * T2[t1] + T1[t1] * T2[f1];
                Kp[i][u] = (uint_t)f2bf(exp2f(la0 * L2E_OVER_T))
                         | ((uint_t)f2bf(exp2f(la1 * L2E_OVER_T)) << 16);
            }
        }
    }
    __syncthreads();   // Tl reads done before Vp (same bytes) is written

    // --- 20 Sinkhorn iterations (2 barriers/iter, R9-verified) ---
    for (int it = 0; it < 20; ++it) {
        float uu[4];
        {
            float4 rv0 = *(const float4*)&rv_p[20 * C + 0];
            float4 rv1 = *(const float4*)&rv_p[20 * C + 4];
            float4 rv2 = *(const float4*)&rv_p[20 * C + 8];
            float4 rv3 = *(const float4*)&rv_p[20 * C + 12];
            #pragma unroll
            for (int i = 0; i < 4; ++i) {
                float a0 = bflo(Kp[i][0]) * rv0.x + bfhi(Kp[i][0]) * rv0.y;
                float a1 = bflo(Kp[i][1]) * rv0.z + bfhi(Kp[i][1]) * rv0.w;
                float a2 = bflo(Kp[i][2]) * rv1.x + bfhi(Kp[i][2]) * rv1.y;
                float a3 = bflo(Kp[i][3]) * rv1.z + bfhi(Kp[i][3]) * rv1.w;
                a0 += bflo(Kp[i][4]) * rv2.x + bfhi(Kp[i][4]) * rv2.y;
                a1 += bflo(Kp[i][5]) * rv2.z + bfhi(Kp[i][5]) * rv2.w;
                a2 += bflo(Kp[i][6]) * rv3.x + bfhi(Kp[i][6]) * rv3.y;
                a3 += bflo(Kp[i][7]) * rv3.z + bfhi(Kp[i][7]) * rv3.w;
                float s = (a0 + a1) + (a2 + a3);
                s = row16_reduce_dpp(s);    // VALU pipe; all 16 lanes hold sum
                uu[i] = frcp(s);
            }
            if (C == 0) {   // ru_s only consumed by the plan phase post-loop
                #pragma unroll
                for (int i = 0; i < 4; ++i) ru_s[4 * R + i] = uu[i];
            }
        }
        {
            #pragma unroll
            for (int h = 0; h < 2; ++h) {
                float pc[8];
                #pragma unroll
                for (int u = 0; u < 4; ++u) {
                    int ui = 4 * h + u;
                    float e0 = bflo(Kp[0][ui]) * uu[0] + bflo(Kp[1][ui]) * uu[1]
                             + bflo(Kp[2][ui]) * uu[2] + bflo(Kp[3][ui]) * uu[3];
                    float e1 = bfhi(Kp[0][ui]) * uu[0] + bfhi(Kp[1][ui]) * uu[1]
                             + bfhi(Kp[2][ui]) * uu[2] + bfhi(Kp[3][ui]) * uu[3];
                    pc[2 * u] = e0; pc[2 * u + 1] = e1;
                }
                #pragma unroll
                for (int k = 0; k < 8; ++k) {
                    float s = pc[k];
                    s += __shfl_xor(s, 16);
                    s += __shfl_xor(s, 32);
                    pc[k] = s;
                }
                if ((t & 63) < 16) {   // one lane per C holds 16-row sums
                    float* dst = &Vp[w * 272 + C * 16 + 8 * h];
                    *(float4*)(dst + 0) = (float4){pc[0], pc[1], pc[2], pc[3]};
                    *(float4*)(dst + 4) = (float4){pc[4], pc[5], pc[6], pc[7]};
                }
            }
        }
        __syncthreads();
        if (t < 256) {   // second stage: sum the 16 wave partials
            float s = 0.f;
            #pragma unroll
            for (int ww = 0; ww < 16; ++ww) s += Vp[ww * 272 + t];
            rv_p[(t >> 4) * 20 + (t & 15)] = frcp(s);
        }
        __syncthreads();
    }

    // --- plan: plan_s[r][j] = K[r][j] * ru[r] * rv[j], j < 24 ---
    int nq = qsz[b]; if (nq > 24) nq = 24;
    int nc = csz[b]; if (nc > 24) nc = 24;

    if (C < 2) {
        int umax = (C == 0) ? 8 : 4;   // C=0: cols 0..15; C=1: cols 16..23
        #pragma unroll
        for (int i = 0; i < 4; ++i) {
            float rr = ru_s[4 * R + i];
            for (int u = 0; u < umax; ++u) {
                int j = 16 * C + 2 * u;
                plan_s[(4 * R + i) * 25 + j]     = bflo(Kp[i][u]) * rr * rv_p[20 * C + 2 * u];
                plan_s[(4 * R + i) * 25 + j + 1] = bfhi(Kp[i][u]) * rr * rv_p[20 * C + 2 * u + 1];
            }
        }
    }
    __syncthreads();

    // --- score: thread = rows 4R..4R+3 x cols 16C..16C+15, 2 d-passes ---
    // q rows = qc[0..23], c rows = qc[24..47]; both via swizzled chunks.
    const int r0 = R * 4;
    const int m  = C;

    float ssum = 0.f;
    #pragma unroll
    for (int p = 0; p < 2; ++p) {
        float ps[32];
        #pragma unroll
        for (int i = 0; i < 32; ++i) ps[i] = 0.f;

        for (int j = 0; j < nc; ++j) {
            float p0 = plan_s[(r0 + 0) * 25 + j];
            float p1 = plan_s[(r0 + 1) * 25 + j];
            float p2 = plan_s[(r0 + 2) * 25 + j];
            float p3 = plan_s[(r0 + 3) * 25 + j];
            const float4* cfp = (const float4*)(qc + (24 + j) * 320 + m * 20) + 2 * p;
            #pragma unroll
            for (int k = 0; k < 2; ++k) {
                float4 cv = cfp[k];
                ps[ 0 + k * 4 + 0] += p0 * cv.x; ps[ 0 + k * 4 + 1] += p0 * cv.y;
                ps[ 0 + k * 4 + 2] += p0 * cv.z; ps[ 0 + k * 4 + 3] += p0 * cv.w;
                ps[ 8 + k * 4 + 0] += p1 * cv.x; ps[ 8 + k * 4 + 1] += p1 * cv.y;
                ps[ 8 + k * 4 + 2] += p1 * cv.z; ps[ 8 + k * 4 + 3] += p1 * cv.w;
                ps[16 + k * 4 + 0] += p2 * cv.x; ps[16 + k * 4 + 1] += p2 * cv.y;
                ps[16 + k * 4 + 2] += p2 * cv.z; ps[16 + k * 4 + 3] += p2 * cv.w;
                ps[24 + k * 4 + 0] += p3 * cv.x; ps[24 + k * 4 + 1] += p3 * cv.y;
                ps[24 + k * 4 + 2] += p3 * cv.z; ps[24 + k * 4 + 3] += p3 * cv.w;
            }
        }

        #pragma unroll
        for (int i = 0; i < 4; ++i) {
            int row = r0 + i;
            if (row < nq) {
                const float4* qp = (const float4*)(qc + row * 320 + m * 20) + 2 * p;
                #pragma unroll
                for (int k = 0; k < 2; ++k) {
                    float4 qv = qp[k];
                    ssum += fmaxf(qv.x - ps[i * 8 + k * 4 + 0], 0.f);
                    ssum += fmaxf(qv.y - ps[i * 8 + k * 4 + 1], 0.f);
                    ssum += fmaxf(qv.z - ps[i * 8 + k * 4 + 2], 0.f);
                    ssum += fmaxf(qv.w - ps[i * 8 + k * 4 + 3], 0.f);
                }
            } else {
                #pragma unroll
                for (int k = 0; k < 8; ++k) ssum += fmaxf(-ps[i * 8 + k], 0.f);
            }
        }
    }

    ssum += __shfl_xor(ssum, 1);
    ssum += __shfl_xor(ssum, 2);
    ssum += __shfl_xor(ssum, 4);
    ssum += __shfl_xor(ssum, 8);
    ssum += __shfl_xor(ssum, 16);
    ssum += __shfl_xor(ssum, 32);
    if ((t & 63) == 0) wsum[t >> 6] = ssum;
    __syncthreads();
    if (t == 0) {
        float s = 0.f;
        #pragma unroll
        for (int i = 0; i < 16; ++i) s += wsum[i];
        out[b] = -s;
    }
}

// ---------------------------------------------------------------------------
extern "C" void kernel_launch(void* const* d_in, const int* in_sizes, int n_in,
                              void* d_out, int out_size, void* d_ws, size_t ws_size,
                              hipStream_t stream)
{
    const float* edge_feat = (const float*)d_in[0];
    const float* tplan     = (const float*)d_in[1];
    const float* W1        = (const float*)d_in[2];
    const float* b1        = (const float*)d_in[3];
    const float* W2        = (const float*)d_in[4];
    const float* b2        = (const float*)d_in[5];
    const int*   from_idx  = (const int*)d_in[6];
    const int*   to_idx    = (const int*)d_in[7];
    const int*   qsz       = (const int*)d_in[9];
    const int*   csz       = (const int*)d_in[10];
    float* out = (float*)d_out;

    // workspace: [0,128K) W1T bf16 | [128K,256K) W2T bf16
    char* ws = (char*)d_ws;
    ushort_t* W1T = (ushort_t*)ws;
    ushort_t* W2T = W1T + 65536;

    prep_w<<<64, 256, 0, stream>>>(W1, W2, W1T, W2T);
    sink_kernel<<<256, 1024, 0, stream>>>(tplan, edge_feat, W1T, W2T, b1, b2,
                                          from_idx, to_idx, qsz, csz, out);
}